// Round 3
// baseline (2125.455 us; speedup 1.0000x reference)
//
#include <hip/hip_runtime.h>
#include <hip/hip_bf16.h>

// ---------------------------------------------------------------------------
// IEGMN layer, MI355X round-11: LDS-staged attention restored, upgraded to
// 64 q-rows/block + register double-buffered staging with raw barriers
// (prefetch next K/V/mask tile into VGPRs while computing current tile).
//   zero_kernel  : zero atomic accumulators + CSR hist/cursors
//   hist_kernel  : per-dst edge histogram
//   scan_kernel  : single-block exclusive scan -> cursors + fp32 counts
//   scatter_kernel: dst-sorted edge permutation (elist)
//   wt_swz       : pack weights fp32[K][256] -> bf16 fragment-ordered blobs
//   edge_mfma    : gather + RBF + edge MLP + coords MLP, dst-sorted order;
//                  per-block segment reduction -> few atomics/block
//   proj_mfma    : q/k/v projections -> bf16 ws (MFMA)
//   kswz_kernel  : K [N][256] -> fragment-ordered blob (16B-chunk permutation)
//   vswz_kernel  : V [N][256] -> fragment-ordered blob (LDS-tiled transpose)
//   attn_mfma    : flash attention partial (split-K), MFMA 16x16x32 bf16,
//                  4 waves x 16 q-rows, double-buffered staging
//   attn_combine : merge splits -> bf16 cross features
//   coords_fin   : x_ev -> out (fp32)
//   node_mfma    : node MLP + skip -> out (fp32, MFMA)
// ---------------------------------------------------------------------------

#define N_LIG   4096
#define N_REC   16384
#define E_LIG_N 65536
#define E_REC_N 262144
#define HD      256
#define ORIGD   64
#define EFD     16
#define NSIG    15
#define EIN     543      // 2*HD + EFD + NSIG
#define XP      552      // edge sX pitch (bf16 elems), 544 used
#define XPN     584      // node sX pitch, 576 used
#define XPP     264      // proj sX pitch, 256 used
#define FP      264      // fp32 reuse pitch inside sX (floats)

typedef __bf16 bf16x8 __attribute__((ext_vector_type(8)));
typedef float  f32x4  __attribute__((ext_vector_type(4)));

__device__ __forceinline__ float lrelu(float x) { return x > 0.f ? x : 0.01f * x; }
__device__ __forceinline__ unsigned short f2bu(float f) {
    __hip_bfloat16 h = __float2bfloat16(f);
    return *reinterpret_cast<unsigned short*>(&h);
}

// ---------------------------------------------------------------------------
// Shared 32xKx256 GEMM core (reg double-buffered).
__device__ __forceinline__ void mfma_gemm(
    const unsigned short* sA, int pitch,
    const __hip_bfloat16* Wswz, int KS, int lane, f32x4 acc[2][4])
{
    const int col = lane & 15, quad = lane >> 4;
    const unsigned short* a0p = sA + (size_t)col * pitch + quad * 8;
    const unsigned short* a1p = sA + (size_t)(16 + col) * pitch + quad * 8;
    const __hip_bfloat16* wp = Wswz + lane * 8;
    bf16x8 bc[4], bn[4], a0c, a1c, a0n, a1n;
    #pragma unroll
    for (int nt = 0; nt < 4; ++nt)
        bc[nt] = *reinterpret_cast<const bf16x8*>(wp + (size_t)nt * KS * 512);
    a0c = *reinterpret_cast<const bf16x8*>(a0p);
    a1c = *reinterpret_cast<const bf16x8*>(a1p);
    for (int ks = 0; ks < KS; ++ks) {
        if (ks + 1 < KS) {
            #pragma unroll
            for (int nt = 0; nt < 4; ++nt)
                bn[nt] = *reinterpret_cast<const bf16x8*>(
                    wp + ((size_t)nt * KS + ks + 1) * 512);
            a0n = *reinterpret_cast<const bf16x8*>(a0p + (ks + 1) * 32);
            a1n = *reinterpret_cast<const bf16x8*>(a1p + (ks + 1) * 32);
        }
        #pragma unroll
        for (int nt = 0; nt < 4; ++nt) {
            acc[0][nt] = __builtin_amdgcn_mfma_f32_16x16x32_bf16(a0c, bc[nt], acc[0][nt], 0, 0, 0);
            acc[1][nt] = __builtin_amdgcn_mfma_f32_16x16x32_bf16(a1c, bc[nt], acc[1][nt], 0, 0, 0);
        }
        #pragma unroll
        for (int nt = 0; nt < 4; ++nt) bc[nt] = bn[nt];
        a0c = a0n; a1c = a1n;
    }
}

// ---------------------------------------------------------------------------
__global__ void zero_kernel(float* __restrict__ p, int n) {
    int i = blockIdx.x * 256 + threadIdx.x;
    if (i < n) p[i] = 0.f;
}

// ---------------------------------------------------------------------------
// CSR build: histogram -> scan -> scatter (dst-sorted edge permutation).
__global__ void hist_kernel(const int* __restrict__ dst, int* __restrict__ hist, int n) {
    int i = blockIdx.x * 256 + threadIdx.x;
    if (i < n) atomicAdd(&hist[dst[i]], 1);
}

__global__ __launch_bounds__(256) void scan_kernel(
    const int* __restrict__ hist, int* __restrict__ cur,
    float* __restrict__ cntf, int n)
{
    __shared__ int part[256];
    const int tid = threadIdx.x;
    const int per = n >> 8;            // n is 4096 or 16384
    const int base = tid * per;
    int s = 0;
    for (int i = 0; i < per; ++i) s += hist[base + i];
    part[tid] = s;
    __syncthreads();
    #pragma unroll
    for (int off = 1; off < 256; off <<= 1) {
        int v = (tid >= off) ? part[tid - off] : 0;
        __syncthreads();
        part[tid] += v;
        __syncthreads();
    }
    int run = part[tid] - s;           // exclusive prefix of this chunk
    for (int i = 0; i < per; ++i) {
        const int h = hist[base + i];
        cur[base + i]  = run;
        cntf[base + i] = (float)h;
        run += h;
    }
}

__global__ void scatter_kernel(const int* __restrict__ dst, int* __restrict__ cur,
                               int* __restrict__ elist, int n) {
    int i = blockIdx.x * 256 + threadIdx.x;
    if (i < n) { int p = atomicAdd(&cur[dst[i]], 1); elist[p] = i; }
}

// ---------------------------------------------------------------------------
__global__ void wt_swz(const float* __restrict__ src,
                       __hip_bfloat16* __restrict__ dst, int K, int KS) {
    const int g  = blockIdx.x / KS;
    const int ks = blockIdx.x % KS;
    for (int i = threadIdx.x; i < 512; i += 256) {
        const int lane = i >> 3, j = i & 7;
        const int n = g * 16 + (lane & 15);
        const int k = ks * 32 + (lane >> 4) * 8 + j;
        const float v = (k < K) ? src[(size_t)k * 256 + n] : 0.f;
        dst[((size_t)(g * KS + ks) * 64 + lane) * 8 + j] = __float2bfloat16(v);
    }
}

// ---------------------------------------------------------------------------
// K fragment swizzle: blob[((key/16)*8+s)*512 + lane*8 + j]
//   = K[(key/16)*16 + (lane&15)][s*32 + (lane>>4)*8 + j].  Pure 16B permute.
__global__ __launch_bounds__(256) void kswz_kernel(
    const __hip_bfloat16* __restrict__ K, __hip_bfloat16* __restrict__ blob)
{
    const int c = blockIdx.x * 256 + threadIdx.x;   // chunk id, N*32 total
    const int lane = c & 63;
    const int s    = (c >> 6) & 7;
    const int kt   = c >> 9;
    const __hip_bfloat16* src =
        K + (size_t)(kt * 16 + (lane & 15)) * HD + s * 32 + (lane >> 4) * 8;
    *reinterpret_cast<uint4*>(blob + (size_t)c * 8) =
        *reinterpret_cast<const uint4*>(src);
}

// ---------------------------------------------------------------------------
// V fragment swizzle: blob[((key32)*16+dt)*512 + lane*8 + j]
//   = V[key32*32 + (lane>>4)*8 + j][dt*16 + (lane&15)].  One 32-key tile/block.
__global__ __launch_bounds__(256) void vswz_kernel(
    const __hip_bfloat16* __restrict__ V, __hip_bfloat16* __restrict__ blob)
{
    __shared__ unsigned short s[32][264];
    const int jt  = blockIdx.x;
    const int tid = threadIdx.x;
    {   // stage V rows [32][256] (b128)
        const int row = tid >> 3;
        const int d0  = (tid & 7) * 32;
        const __hip_bfloat16* vp = V + (size_t)(jt * 32 + row) * HD + d0;
        #pragma unroll
        for (int i = 0; i < 4; ++i)
            *reinterpret_cast<uint4*>(&s[row][d0 + 8 * i]) =
                *reinterpret_cast<const uint4*>(vp + 8 * i);
    }
    __syncthreads();
    {
        const int w    = tid >> 6;
        const int lane = tid & 63;
        const int col  = lane & 15;
        const int quad = lane >> 4;
        #pragma unroll
        for (int i = 0; i < 4; ++i) {
            const int dt = w + i * 4;
            unsigned short tmp[8];
            #pragma unroll
            for (int j = 0; j < 8; ++j)
                tmp[j] = s[quad * 8 + j][dt * 16 + col];
            *reinterpret_cast<uint4*>(
                blob + ((size_t)(jt * 16 + dt) * 64 + lane) * 8) =
                *reinterpret_cast<uint4*>(tmp);
        }
    }
}

// ---------------------------------------------------------------------------
// Edge MFMA kernel: 32 edges/block, edges taken in dst-sorted order (elist).
__global__ __launch_bounds__(256, 4) void edge_mfma(
    const float* __restrict__ coords, const float* __restrict__ h,
    const float* __restrict__ ef,
    const int* __restrict__ src, const int* __restrict__ dst,
    const int* __restrict__ elist,
    const __hip_bfloat16* __restrict__ W1s, const float* __restrict__ b1,
    const __hip_bfloat16* __restrict__ W2s, const float* __restrict__ b2,
    const __hip_bfloat16* __restrict__ Wc1s, const float* __restrict__ bc1,
    const float* __restrict__ wc2v, const float* __restrict__ bc2,
    float* __restrict__ aggr, float* __restrict__ xsum)
{
    __shared__ unsigned short sX[32][XP];     // also reused as fp32 [32][FP]
    __shared__ float sXrel[32][3];
    __shared__ int   sDst[32];
    __shared__ int   sSrc[32];
    __shared__ int   sE[32];
    __shared__ float sRedW[4][32];
    __shared__ float sPv[32];

    const int tid  = threadIdx.x;
    const int lane = tid & 63;
    const int wave = tid >> 6;
    const int col  = lane & 15;
    const int quad = lane >> 4;
    const int e0   = blockIdx.x * 32;

    // ---- edge meta: permuted id, endpoints, x_rel, RBF ----
    if (tid < 32) {
        const int e = elist[e0 + tid];
        const int s = src[e], d = dst[e];
        sE[tid] = e; sSrc[tid] = s; sDst[tid] = d;
        float d2 = 0.f;
        #pragma unroll
        for (int c = 0; c < 3; ++c) {
            const float xr = coords[s * 3 + c] - coords[d * 3 + c];
            sXrel[tid][c] = xr;
            d2 += xr * xr;
        }
        float sig = 1.0f;
        #pragma unroll
        for (int si = 0; si < NSIG; ++si) {
            sX[tid][528 + si] = f2bu(__expf(-d2 / sig));
            sig *= 1.5f;
        }
        sX[tid][543] = 0;
    }
    __syncthreads();

    // ---- gather h[src], h[dst] ----
    for (int i = tid; i < 32 * 128; i += 256) {
        const int row = i >> 7, c4 = i & 127;
        const int node = (c4 < 64) ? sSrc[row] : sDst[row];
        const float4 v = *reinterpret_cast<const float4*>(
            &h[(size_t)node * HD + (c4 & 63) * 4]);
        ushort4 u = { f2bu(v.x), f2bu(v.y), f2bu(v.z), f2bu(v.w) };
        *reinterpret_cast<ushort4*>(&sX[row][c4 * 4]) = u;
    }
    // ---- gather edge features (permuted rows) ----
    if (tid < 128) {
        const int row = tid >> 2, c = tid & 3;
        const float4 v = *reinterpret_cast<const float4*>(
            &ef[(size_t)sE[row] * EFD + c * 4]);
        ushort4 u = { f2bu(v.x), f2bu(v.y), f2bu(v.z), f2bu(v.w) };
        *reinterpret_cast<ushort4*>(&sX[row][512 + c * 4]) = u;
    }
    __syncthreads();

    f32x4 acc[2][4];
    f32x4 macc[2][4];   // message accumulators, survive the coords GEMM

    // ---- GEMM1: [32 x 544] @ W1 -> hidden, lrelu ----
    #pragma unroll
    for (int nt = 0; nt < 4; ++nt) {
        const float bv = b1[wave * 64 + nt * 16 + col];
        acc[0][nt] = { bv, bv, bv, bv };
        acc[1][nt] = { bv, bv, bv, bv };
    }
    mfma_gemm(&sX[0][0], XP, W1s + (size_t)(wave * 4) * 17 * 512, 17, lane, acc);
    __syncthreads();
    #pragma unroll
    for (int mt = 0; mt < 2; ++mt)
        #pragma unroll
        for (int nt = 0; nt < 4; ++nt)
            #pragma unroll
            for (int r = 0; r < 4; ++r)
                sX[mt * 16 + quad * 4 + r][wave * 64 + nt * 16 + col] =
                    f2bu(lrelu(acc[mt][nt][r]));
    __syncthreads();

    // ---- GEMM2: hidden @ W2 -> msg (kept fp32 in macc) ----
    #pragma unroll
    for (int nt = 0; nt < 4; ++nt) {
        const float bv = b2[wave * 64 + nt * 16 + col];
        macc[0][nt] = { bv, bv, bv, bv };
        macc[1][nt] = { bv, bv, bv, bv };
    }
    mfma_gemm(&sX[0][0], XP, W2s + (size_t)(wave * 4) * 8 * 512, 8, lane, macc);
    __syncthreads();
    #pragma unroll
    for (int mt = 0; mt < 2; ++mt)
        #pragma unroll
        for (int nt = 0; nt < 4; ++nt)
            #pragma unroll
            for (int r = 0; r < 4; ++r)
                sX[mt * 16 + quad * 4 + r][wave * 64 + nt * 16 + col] =
                    f2bu(macc[mt][nt][r]);
    __syncthreads();

    // ---- GEMM3: msg @ Wc1 -> lrelu -> dot wc2 (per-edge scalar p) ----
    #pragma unroll
    for (int nt = 0; nt < 4; ++nt) {
        const float bv = bc1[wave * 64 + nt * 16 + col];
        acc[0][nt] = { bv, bv, bv, bv };
        acc[1][nt] = { bv, bv, bv, bv };
    }
    mfma_gemm(&sX[0][0], XP, Wc1s + (size_t)(wave * 4) * 8 * 512, 8, lane, acc);
    float w2l[4];
    #pragma unroll
    for (int nt = 0; nt < 4; ++nt) w2l[nt] = wc2v[wave * 64 + nt * 16 + col];
    #pragma unroll
    for (int mt = 0; mt < 2; ++mt) {
        float pr[4] = { 0.f, 0.f, 0.f, 0.f };
        #pragma unroll
        for (int nt = 0; nt < 4; ++nt)
            #pragma unroll
            for (int r = 0; r < 4; ++r)
                pr[r] += lrelu(acc[mt][nt][r]) * w2l[nt];
        #pragma unroll
        for (int r = 0; r < 4; ++r) {
            #pragma unroll
            for (int off = 1; off < 16; off <<= 1) pr[r] += __shfl_xor(pr[r], off);
        }
        if (col == 0)
            #pragma unroll
            for (int r = 0; r < 4; ++r)
                sRedW[wave][mt * 16 + quad * 4 + r] = pr[r];
    }
    __syncthreads();

    // ---- dump fp32 messages into LDS (reuse sX), gather p per edge ----
    float* sF = reinterpret_cast<float*>(&sX[0][0]);   // [32][FP] floats
    #pragma unroll
    for (int mt = 0; mt < 2; ++mt)
        #pragma unroll
        for (int nt = 0; nt < 4; ++nt)
            #pragma unroll
            for (int r = 0; r < 4; ++r)
                sF[(mt * 16 + quad * 4 + r) * FP + wave * 64 + nt * 16 + col] =
                    macc[mt][nt][r];
    if (tid < 32)
        sPv[tid] = sRedW[0][tid] + sRedW[1][tid] + sRedW[2][tid] + sRedW[3][tid]
                 + bc2[0];
    __syncthreads();

    // ---- segmented flush: one atomic per (distinct dst x column) ----
    {
        const int c = tid;               // 256 threads = 256 columns
        float av = 0.f;
        int dprev = sDst[0];
        for (int row = 0; row < 32; ++row) {
            const int d = sDst[row];     // uniform across block -> no divergence
            if (d != dprev) {
                atomicAdd(&aggr[(size_t)dprev * HD + c], av);
                av = 0.f; dprev = d;
            }
            av += sF[row * FP + c];
        }
        atomicAdd(&aggr[(size_t)dprev * HD + c], av);
    }
    if (tid < 3) {
        const int c = tid;
        float av = 0.f;
        int dprev = sDst[0];
        for (int row = 0; row < 32; ++row) {
            const int d = sDst[row];
            if (d != dprev) {
                atomicAdd(&xsum[(size_t)dprev * 3 + c], av);
                av = 0.f; dprev = d;
            }
            av += sXrel[row][c] * sPv[row];
        }
        atomicAdd(&xsum[(size_t)dprev * 3 + c], av);
    }
}

// ---------------------------------------------------------------------------
// Node MFMA kernel: 32 nodes/block (unchanged).
__global__ __launch_bounds__(256, 4) void node_mfma(
    const float* __restrict__ aggr, const float* __restrict__ cnt,
    const __hip_bfloat16* __restrict__ cross, const float* __restrict__ orig,
    const float* __restrict__ hfeat,
    const __hip_bfloat16* __restrict__ WN1s, const float* __restrict__ b1,
    const __hip_bfloat16* __restrict__ WN2s, const float* __restrict__ b2,
    float* __restrict__ out)
{
    __shared__ unsigned short sXn[32][XPN];
    __shared__ float sInv[32];

    const int tid  = threadIdx.x;
    const int lane = tid & 63;
    const int wave = tid >> 6;
    const int col  = lane & 15;
    const int quad = lane >> 4;
    const int r0   = blockIdx.x * 32;

    if (tid < 32) sInv[tid] = 1.f / fmaxf(cnt[r0 + tid], 1.f);
    __syncthreads();

    for (int i = tid; i < 32 * 64; i += 256) {
        const int row = i >> 6, c4 = i & 63;
        const float inv = sInv[row];
        const float4 v = *reinterpret_cast<const float4*>(
            &aggr[(size_t)(r0 + row) * HD + c4 * 4]);
        ushort4 u = { f2bu(v.x * inv), f2bu(v.y * inv), f2bu(v.z * inv), f2bu(v.w * inv) };
        *reinterpret_cast<ushort4*>(&sXn[row][c4 * 4]) = u;
    }
    for (int i = tid; i < 32 * 64; i += 256) {
        const int row = i >> 6, c4 = i & 63;
        const ushort4 u = *reinterpret_cast<const ushort4*>(
            &cross[(size_t)(r0 + row) * HD + c4 * 4]);
        *reinterpret_cast<ushort4*>(&sXn[row][256 + c4 * 4]) = u;
    }
    for (int i = tid; i < 32 * 16; i += 256) {
        const int row = i >> 4, c4 = i & 15;
        const float4 v = *reinterpret_cast<const float4*>(
            &orig[(size_t)(r0 + row) * ORIGD + c4 * 4]);
        ushort4 u = { f2bu(v.x), f2bu(v.y), f2bu(v.z), f2bu(v.w) };
        *reinterpret_cast<ushort4*>(&sXn[row][512 + c4 * 4]) = u;
    }
    __syncthreads();

    f32x4 acc[2][4];

    #pragma unroll
    for (int nt = 0; nt < 4; ++nt) {
        const float bv = b1[wave * 64 + nt * 16 + col];
        acc[0][nt] = { bv, bv, bv, bv };
        acc[1][nt] = { bv, bv, bv, bv };
    }
    mfma_gemm(&sXn[0][0], XPN, WN1s + (size_t)(wave * 4) * 18 * 512, 18, lane, acc);
    __syncthreads();
    #pragma unroll
    for (int mt = 0; mt < 2; ++mt)
        #pragma unroll
        for (int nt = 0; nt < 4; ++nt)
            #pragma unroll
            for (int r = 0; r < 4; ++r)
                sXn[mt * 16 + quad * 4 + r][wave * 64 + nt * 16 + col] =
                    f2bu(lrelu(acc[mt][nt][r]));
    __syncthreads();

    #pragma unroll
    for (int nt = 0; nt < 4; ++nt) {
        const float bv = b2[wave * 64 + nt * 16 + col];
        acc[0][nt] = { bv, bv, bv, bv };
        acc[1][nt] = { bv, bv, bv, bv };
    }
    mfma_gemm(&sXn[0][0], XPN, WN2s + (size_t)(wave * 4) * 8 * 512, 8, lane, acc);
    #pragma unroll
    for (int mt = 0; mt < 2; ++mt)
        #pragma unroll
        for (int nt = 0; nt < 4; ++nt)
            #pragma unroll
            for (int r = 0; r < 4; ++r) {
                const int g = r0 + mt * 16 + quad * 4 + r;
                const int n = wave * 64 + nt * 16 + col;
                out[(size_t)g * HD + n] =
                    0.5f * acc[mt][nt][r] + 0.5f * hfeat[(size_t)g * HD + n];
            }
}

// ---------------------------------------------------------------------------
// Projection MFMA (unchanged).
__global__ __launch_bounds__(256, 4) void proj_mfma(
    const float* __restrict__ X, const __hip_bfloat16* __restrict__ Ws,
    __hip_bfloat16* __restrict__ out, int applyLrelu)
{
    __shared__ unsigned short sXp[32][XPP];
    const int tid  = threadIdx.x;
    const int lane = tid & 63;
    const int wave = tid >> 6;
    const int col  = lane & 15;
    const int quad = lane >> 4;
    const int r0   = blockIdx.x * 32;

    for (int i = tid; i < 32 * 64; i += 256) {
        const int row = i >> 6, c4 = i & 63;
        const float4 v = *reinterpret_cast<const float4*>(
            &X[(size_t)(r0 + row) * HD + c4 * 4]);
        ushort4 u = { f2bu(v.x), f2bu(v.y), f2bu(v.z), f2bu(v.w) };
        *reinterpret_cast<ushort4*>(&sXp[row][c4 * 4]) = u;
    }
    __syncthreads();

    f32x4 acc[2][4];
    #pragma unroll
    for (int nt = 0; nt < 4; ++nt) {
        acc[0][nt] = { 0.f, 0.f, 0.f, 0.f };
        acc[1][nt] = { 0.f, 0.f, 0.f, 0.f };
    }
    mfma_gemm(&sXp[0][0], XPP, Ws + (size_t)(wave * 4) * 8 * 512, 8, lane, acc);
    #pragma unroll
    for (int mt = 0; mt < 2; ++mt)
        #pragma unroll
        for (int nt = 0; nt < 4; ++nt)
            #pragma unroll
            for (int r = 0; r < 4; ++r) {
                float v = acc[mt][nt][r];
                if (applyLrelu) v = lrelu(v);
                out[(size_t)(r0 + mt * 16 + quad * 4 + r) * HD +
                    wave * 64 + nt * 16 + col] = __float2bfloat16(v);
            }
}

// ---------------------------------------------------------------------------
// MFMA flash attention partial. 64 q-rows/block (4 waves x 16), 32-key tiles.
// K/V/mask staged through LDS, register double-buffered: while tile t is
// computed, tile t+1's global loads are already in flight into VGPRs.
// Raw s_barrier (no vmcnt drain) + explicit lgkmcnt keeps the prefetch
// in flight across the barrier; vmcnt wait lands at the ds_write (reg dep).
__global__ __launch_bounds__(256, 2) void attn_mfma(
    const __hip_bfloat16* __restrict__ Qb, const __hip_bfloat16* __restrict__ Kz,
    const __hip_bfloat16* __restrict__ Vz, const float* __restrict__ maskG,
    float* __restrict__ PO, float* __restrict__ PM, float* __restrict__ PL,
    int M, int chunkKeys, int transposed)
{
    __shared__ unsigned short sKb[8192];      // 16 KB: 2 keytiles x 8 slices x 512
    __shared__ unsigned short sVb[8192];      // 16 KB: 16 dgroups x 512
    __shared__ unsigned short sP[4][16][40];
    __shared__ float          sMask[4][16][36];

    const int tid  = threadIdx.x;
    const int lane = tid & 63;
    const int wave = tid >> 6;
    const int col  = lane & 15;
    const int quad = lane >> 4;
    const int R0   = blockIdx.x * 64;
    const int split = blockIdx.y;
    const int jbase = split * chunkKeys;

    bf16x8 qf[8];
    {
        const __hip_bfloat16* qp =
            Qb + (size_t)(R0 + wave * 16 + col) * HD + quad * 8;
        #pragma unroll
        for (int s = 0; s < 8; ++s)
            qf[s] = *reinterpret_cast<const bf16x8*>(qp + 32 * s);
    }

    f32x4 o[16];
    #pragma unroll
    for (int dt = 0; dt < 16; ++dt) { o[dt][0]=0.f; o[dt][1]=0.f; o[dt][2]=0.f; o[dt][3]=0.f; }
    float m[4], l[4];
    #pragma unroll
    for (int r = 0; r < 4; ++r) { m[r] = -INFINITY; l[r] = 0.f; }

    // mask staging coords (per thread)
    const int mrow = tid >> 2;            // !transposed: q-row 0..63
    const int mc0  = (tid & 3) * 8;       // !transposed: key offset
    const int mkey = tid >> 3;            // transposed: key 0..31
    const int mrb  = (tid & 7) * 8;       // transposed: q-row base

    uint4 kvreg[8];
    float4 mreg[2];

    // ---- prologue: issue tile-0 loads into regs ----
    {
        const uint4* ksrc = reinterpret_cast<const uint4*>(Kz + (size_t)jbase * 256);
        const uint4* vsrc = reinterpret_cast<const uint4*>(Vz + (size_t)jbase * 256);
        #pragma unroll
        for (int i = 0; i < 4; ++i) {
            kvreg[i]     = ksrc[tid + 256 * i];
            kvreg[4 + i] = vsrc[tid + 256 * i];
        }
        if (!transposed) {
            #pragma unroll
            for (int i = 0; i < 2; ++i)
                mreg[i] = *reinterpret_cast<const float4*>(
                    &maskG[(size_t)(R0 + mrow) * N_REC + jbase + mc0 + 4 * i]);
        } else {
            #pragma unroll
            for (int i = 0; i < 2; ++i)
                mreg[i] = *reinterpret_cast<const float4*>(
                    &maskG[(size_t)(jbase + mkey) * N_REC + R0 + mrb + 4 * i]);
        }
    }

    for (int jt = 0; jt < chunkKeys; jt += 32) {
        __builtin_amdgcn_s_barrier();          // all waves done reading prev tile
        // ---- write staged regs -> LDS (vmcnt wait lands here via reg deps) ----
        {
            uint4* kdst = reinterpret_cast<uint4*>(sKb);
            uint4* vdst = reinterpret_cast<uint4*>(sVb);
            #pragma unroll
            for (int i = 0; i < 4; ++i) {
                kdst[tid + 256 * i] = kvreg[i];
                vdst[tid + 256 * i] = kvreg[4 + i];
            }
            if (!transposed) {
                #pragma unroll
                for (int i = 0; i < 2; ++i)
                    *reinterpret_cast<float4*>(&sMask[mrow >> 4][mrow & 15][mc0 + 4 * i]) =
                        mreg[i];
            } else {
                float mv[8];
                *reinterpret_cast<float4*>(&mv[0]) = mreg[0];
                *reinterpret_cast<float4*>(&mv[4]) = mreg[1];
                #pragma unroll
                for (int u = 0; u < 8; ++u) {
                    const int row = mrb + u;
                    sMask[row >> 4][row & 15][mkey] = mv[u];
                }
            }
        }
        // ---- issue next tile's loads ----
        {
            const int jn = (jt + 32 < chunkKeys) ? jbase + jt + 32 : jbase + jt;
            const uint4* ksrc = reinterpret_cast<const uint4*>(Kz + (size_t)jn * 256);
            const uint4* vsrc = reinterpret_cast<const uint4*>(Vz + (size_t)jn * 256);
            #pragma unroll
            for (int i = 0; i < 4; ++i) {
                kvreg[i]     = ksrc[tid + 256 * i];
                kvreg[4 + i] = vsrc[tid + 256 * i];
            }
            if (!transposed) {
                #pragma unroll
                for (int i = 0; i < 2; ++i)
                    mreg[i] = *reinterpret_cast<const float4*>(
                        &maskG[(size_t)(R0 + mrow) * N_REC + jn + mc0 + 4 * i]);
            } else {
                #pragma unroll
                for (int i = 0; i < 2; ++i)
                    mreg[i] = *reinterpret_cast<const float4*>(
                        &maskG[(size_t)(jn + mkey) * N_REC + R0 + mrb + 4 * i]);
            }
        }
        asm volatile("s_waitcnt lgkmcnt(0)" ::: "memory");  // LDS writes visible
        __builtin_amdgcn_s_barrier();
        __builtin_amdgcn_sched_barrier(0);

        // ---- S = Q K^T ----
        f32x4 sacc[2];
        sacc[0][0]=0.f; sacc[0][1]=0.f; sacc[0][2]=0.f; sacc[0][3]=0.f;
        sacc[1][0]=0.f; sacc[1][1]=0.f; sacc[1][2]=0.f; sacc[1][3]=0.f;
        #pragma unroll
        for (int t = 0; t < 2; ++t) {
            #pragma unroll
            for (int s = 0; s < 8; ++s) {
                bf16x8 kf = *reinterpret_cast<const bf16x8*>(
                    &sKb[(t * 8 + s) * 512 + lane * 8]);
                sacc[t] = __builtin_amdgcn_mfma_f32_16x16x32_bf16(qf[s], kf, sacc[t], 0, 0, 0);
            }
        }

        // ---- online softmax ----
        float a[2][4];
        #pragma unroll
        for (int t = 0; t < 2; ++t)
            #pragma unroll
            for (int r = 0; r < 4; ++r) {
                const float mv = sMask[wave][quad * 4 + r][col + 16 * t];
                a[t][r] = mv * sacc[t][r] - 1000.f * (1.f - mv);
            }
        #pragma unroll
        for (int r = 0; r < 4; ++r) {
            float mx = fmaxf(a[0][r], a[1][r]);
            #pragma unroll
            for (int off = 1; off < 16; off <<= 1)
                mx = fmaxf(mx, __shfl_xor(mx, off));
            const float mn = fmaxf(m[r], mx);
            const float c  = __expf(m[r] - mn);
            m[r] = mn;
            const float p0 = __expf(a[0][r] - mn);
            const float p1 = __expf(a[1][r] - mn);
            sP[wave][quad * 4 + r][col]      = f2bu(p0);
            sP[wave][quad * 4 + r][col + 16] = f2bu(p1);
            float ps = p0 + p1;
            #pragma unroll
            for (int off = 1; off < 16; off <<= 1)
                ps += __shfl_xor(ps, off);
            l[r] = l[r] * c + ps;
            #pragma unroll
            for (int dt = 0; dt < 16; ++dt) o[dt][r] *= c;
        }

        // ---- O += P V ----
        bf16x8 pf = *reinterpret_cast<const bf16x8*>(&sP[wave][col][quad * 8]);
        #pragma unroll
        for (int dt = 0; dt < 16; ++dt) {
            bf16x8 vf = *reinterpret_cast<const bf16x8*>(&sVb[dt * 512 + lane * 8]);
            o[dt] = __builtin_amdgcn_mfma_f32_16x16x32_bf16(pf, vf, o[dt], 0, 0, 0);
        }
    }

    #pragma unroll
    for (int dt = 0; dt < 16; ++dt)
        #pragma unroll
        for (int r = 0; r < 4; ++r) {
            const int row = R0 + wave * 16 + quad * 4 + r;
            PO[((size_t)split * M + row) * HD + dt * 16 + col] = o[dt][r];
        }
    if (col == 0) {
        #pragma unroll
        for (int r = 0; r < 4; ++r) {
            const int row = R0 + wave * 16 + quad * 4 + r;
            PM[(size_t)split * M + row] = m[r];
            PL[(size_t)split * M + row] = l[r];
        }
    }
}

// ---------------------------------------------------------------------------
__global__ void attn_combine(
    const float* __restrict__ PO, const float* __restrict__ PM,
    const float* __restrict__ PL, __hip_bfloat16* __restrict__ Out,
    int M, int nchunks)
{
    const int idx = blockIdx.x * 256 + threadIdx.x;
    const int row = idx >> 8;
    float mmax = -INFINITY;
    for (int c = 0; c < nchunks; ++c) mmax = fmaxf(mmax, PM[(size_t)c * M + row]);
    float denom = 0.f, acc = 0.f;
    for (int c = 0; c < nchunks; ++c) {
        const float w = __expf(PM[(size_t)c * M + row] - mmax);
        denom += PL[(size_t)c * M + row] * w;
        acc   += PO[(size_t)c * M * HD + idx] * w;
    }
    Out[idx] = __float2bfloat16(acc / denom);
}

// ---------------------------------------------------------------------------
__global__ void coords_fin(
    const float* __restrict__ coords, const float* __restrict__ origc,
    const float* __restrict__ xsum, const float* __restrict__ cnt,
    float* __restrict__ out, int n)
{
    const int i = blockIdx.x * 256 + threadIdx.x;
    if (i >= n * 3) return;
    const int node = i / 3;
    const float inv = 1.f / fmaxf(cnt[node], 1.f);
    out[i] = 0.25f * origc[i] + 0.75f * coords[i] + xsum[i] * inv;
}

// ---------------------------------------------------------------------------
extern "C" void kernel_launch(void* const* d_in, const int* in_sizes, int n_in,
                              void* d_out, int out_size, void* d_ws, size_t ws_size,
                              hipStream_t stream)
{
    const float* coords_lig = (const float*)d_in[0];
    const float* h_lig      = (const float*)d_in[1];
    const float* orig_lig   = (const float*)d_in[2];
    const float* origc_lig  = (const float*)d_in[3];
    const float* coords_rec = (const float*)d_in[4];
    const float* h_rec      = (const float*)d_in[5];
    const float* orig_rec   = (const float*)d_in[6];
    const float* origc_rec  = (const float*)d_in[7];
    const float* mask       = (const float*)d_in[8];
    const float* lig_ef     = (const float*)d_in[9];
    const float* rec_ef     = (const float*)d_in[10];
    const int* lig_src = (const int*)d_in[11];
    const int* lig_dst = (const int*)d_in[12];
    const int* rec_src = (const int*)d_in[13];
    const int* rec_dst = (const int*)d_in[14];
    const float* le_w1 = (const float*)d_in[15];
    const float* le_b1 = (const float*)d_in[16];
    const float* le_w2 = (const float*)d_in[17];
    const float* le_b2 = (const float*)d_in[18];
    const float* re_w1 = (const float*)d_in[19];
    const float* re_b1 = (const float*)d_in[20];
    const float* re_w2 = (const float*)d_in[21];
    const float* re_b2 = (const float*)d_in[22];
    const float* aql_w = (const float*)d_in[23];
    const float* akl_w = (const float*)d_in[24];
    const float* avl_w = (const float*)d_in[25];
    const float* aqr_w = (const float*)d_in[26];
    const float* akr_w = (const float*)d_in[27];
    const float* avr_w = (const float*)d_in[28];
    const float* nl_w1 = (const float*)d_in[29];
    const float* nl_b1 = (const float*)d_in[30];
    const float* nl_w2 = (const float*)d_in[31];
    const float* nl_b2 = (const float*)d_in[32];
    const float* nr_w1 = (const float*)d_in[33];
    const float* nr_b1 = (const float*)d_in[34];
    const float* nr_w2 = (const float*)d_in[35];
    const float* nr_b2 = (const float*)d_in[36];
    const float* cl_w1 = (const float*)d_in[37];
    const float* cl_b1 = (const float*)d_in[38];
    const float* cl_w2 = (const float*)d_in[39];
    const float* cl_b2 = (const float*)d_in[40];
    const float* cr_w1 = (const float*)d_in[41];
    const float* cr_b1 = (const float*)d_in[42];
    const float* cr_w2 = (const float*)d_in[43];
    const float* cr_b2 = (const float*)d_in[44];

    float* out = (float*)d_out;
    float* wsf = (float*)d_ws;

    // ---- fp32 accumulator + CSR zone ----
    const size_t AGGRL = 0;
    const size_t AGGRR = AGGRL + (size_t)N_LIG * HD;
    const size_t CNTL  = AGGRR + (size_t)N_REC * HD;
    const size_t CNTR  = CNTL + N_LIG;
    const size_t XSUML = CNTR + N_REC;
    const size_t XSUMR = XSUML + (size_t)N_LIG * 3;
    const size_t HISTL = XSUMR + (size_t)N_REC * 3;
    const size_t CURL  = HISTL + N_LIG;
    const size_t HISTR = CURL + N_LIG;
    const size_t CURR  = HISTR + N_REC;
    const size_t ZEND  = CURR + N_REC;          // zeroed through here
    const size_t ELISTL = ZEND;                 // not zeroed
    const size_t ELISTR = ELISTL + E_LIG_N;
    const size_t FEND   = ELISTR + E_REC_N;

    // ---- bf16 zone ----
    __hip_bfloat16* wsb = (__hip_bfloat16*)(wsf + FEND);
    const size_t QL  = 0;
    const size_t KL  = QL + (size_t)N_LIG * HD;
    const size_t VL  = KL + (size_t)N_LIG * HD;
    const size_t QR  = VL + (size_t)N_LIG * HD;
    const size_t KR  = QR + (size_t)N_REC * HD;
    const size_t VR  = KR + (size_t)N_REC * HD;
    const size_t CRL = VR + (size_t)N_REC * HD;
    const size_t CRR = CRL + (size_t)N_LIG * HD;
    const size_t KZL = CRR + (size_t)N_REC * HD;          // K swizzled lig
    const size_t VZL = KZL + (size_t)N_LIG * HD;          // V swizzled lig
    const size_t KZR = VZL + (size_t)N_LIG * HD;          // K swizzled rec
    const size_t VZR = KZR + (size_t)N_REC * HD;          // V swizzled rec
    const size_t EW1SZ = (size_t)16 * 17 * 512;
    const size_t KW256 = (size_t)16 * 8 * 512;
    const size_t NW1SZ = (size_t)16 * 18 * 512;
    const size_t SW_EL1 = VZR + (size_t)N_REC * HD;
    const size_t SW_EL2 = SW_EL1 + EW1SZ;
    const size_t SW_EC1 = SW_EL2 + KW256;
    const size_t SW_NL1 = SW_EC1 + KW256;
    const size_t SW_NL2 = SW_NL1 + NW1SZ;
    const size_t SW_ER1 = SW_NL2 + KW256;
    const size_t SW_ER2 = SW_ER1 + EW1SZ;
    const size_t SW_EC1R = SW_ER2 + KW256;
    const size_t SW_NR1 = SW_EC1R + KW256;
    const size_t SW_NR2 = SW_NR1 + NW1SZ;
    const size_t SW_PQL = SW_NR2 + KW256;
    const size_t SW_PKL = SW_PQL + KW256;
    const size_t SW_PVL = SW_PKL + KW256;
    const size_t SW_PQR = SW_PVL + KW256;
    const size_t SW_PKR = SW_PQR + KW256;
    const size_t SW_PVR = SW_PKR + KW256;
    const size_t BF_END = SW_PVR + KW256;

    // ---- split-K partial zone (fp32), dynamic splits ----
    float* wsp = (float*)(wsb + ((BF_END + 1) & ~(size_t)1));
    const size_t baseBytes = (size_t)((char*)wsp - (char*)d_ws);
    int SL = 16, SR = 4;
    {
        const size_t poElems16 = (size_t)16 * N_LIG * HD;
        const size_t need16 = baseBytes +
            (poElems16 + 2 * (size_t)16 * N_LIG) * sizeof(float);
        if (ws_size < need16) { SL = 8; SR = 2; }
    }
    const size_t PO_ = 0;
    const size_t PM_ = PO_ + (size_t)SL * N_LIG * HD;
    const size_t PL_ = PM_ + (size_t)SL * N_LIG;

    const size_t O_XL = 0;
    const size_t O_HL = O_XL + (size_t)N_LIG * 3;
    const size_t O_XR = O_HL + (size_t)N_LIG * HD;
    const size_t O_HR = O_XR + (size_t)N_REC * 3;

    // 1) zero atomic accumulators + CSR hist/cursors
    zero_kernel<<<((int)ZEND + 255) / 256, 256, 0, stream>>>(wsf, (int)ZEND);

    // 1b) CSR build: dst-sorted edge permutations (also produces fp32 counts)
    hist_kernel<<<E_LIG_N / 256, 256, 0, stream>>>(lig_dst, (int*)(wsf + HISTL), E_LIG_N);
    hist_kernel<<<E_REC_N / 256, 256, 0, stream>>>(rec_dst, (int*)(wsf + HISTR), E_REC_N);
    scan_kernel<<<1, 256, 0, stream>>>((int*)(wsf + HISTL), (int*)(wsf + CURL),
                                       wsf + CNTL, N_LIG);
    scan_kernel<<<1, 256, 0, stream>>>((int*)(wsf + HISTR), (int*)(wsf + CURR),
                                       wsf + CNTR, N_REC);
    scatter_kernel<<<E_LIG_N / 256, 256, 0, stream>>>(
        lig_dst, (int*)(wsf + CURL), (int*)(wsf + ELISTL), E_LIG_N);
    scatter_kernel<<<E_REC_N / 256, 256, 0, stream>>>(
        rec_dst, (int*)(wsf + CURR), (int*)(wsf + ELISTR), E_REC_N);

    // 2) weight swizzles
    wt_swz<<<16 * 17, 256, 0, stream>>>(le_w1, wsb + SW_EL1, EIN, 17);
    wt_swz<<<16 * 8,  256, 0, stream>>>(le_w2, wsb + SW_EL2, 256, 8);
    wt_swz<<<16 * 8,  256, 0, stream>>>(cl_w1, wsb + SW_EC1, 256, 8);
    wt_swz<<<16 * 18, 256, 0, stream>>>(nl_w1, wsb + SW_NL1, 576, 18);
    wt_swz<<<16 * 8,  256, 0, stream>>>(nl_w2, wsb + SW_NL2, 256, 8);
    wt_swz<<<16 * 17, 256, 0, stream>>>(re_w1, wsb + SW_ER1, EIN, 17);
    wt_swz<<<16 * 8,  256, 0, stream>>>(re_w2, wsb + SW_ER2, 256, 8);
    wt_swz<<<16 * 8,  256, 0, stream>>>(cr_w1, wsb + SW_EC1R, 256, 8);
    wt_swz<<<16 * 18, 256, 0, stream>>>(nr_w1, wsb + SW_NR1, 576, 18);
    wt_swz<<<16 * 8,  256, 0, stream>>>(nr_w2, wsb + SW_NR2, 256, 8);
    wt_swz<<<16 * 8,  256, 0, stream>>>(aql_w, wsb + SW_PQL, 256, 8);
    wt_swz<<<16 * 8,  256, 0, stream>>>(akl_w, wsb + SW_PKL, 256, 8);
    wt_swz<<<16 * 8,  256, 0, stream>>>(avl_w, wsb + SW_PVL, 256, 8);
    wt_swz<<<16 * 8,  256, 0, stream>>>(aqr_w, wsb + SW_PQR, 256, 8);
    wt_swz<<<16 * 8,  256, 0, stream>>>(akr_w, wsb + SW_PKR, 256, 8);
    wt_swz<<<16 * 8,  256, 0, stream>>>(avr_w, wsb + SW_PVR, 256, 8);

    // 3) edge MFMA kernels (dst-sorted order, segmented atomics)
    edge_mfma<<<E_LIG_N / 32, 256, 0, stream>>>(
        coords_lig, h_lig, lig_ef, lig_src, lig_dst, (const int*)(wsf + ELISTL),
        wsb + SW_EL1, le_b1, wsb + SW_EL2, le_b2, wsb + SW_EC1, cl_b1, cl_w2, cl_b2,
        wsf + AGGRL, wsf + XSUML);
    edge_mfma<<<E_REC_N / 32, 256, 0, stream>>>(
        coords_rec, h_rec, rec_ef, rec_src, rec_dst, (const int*)(wsf + ELISTR),
        wsb + SW_ER1, re_b1, wsb + SW_ER2, re_b2, wsb + SW_EC1R, cr_b1, cr_w2, cr_b2,
        wsf + AGGRR, wsf + XSUMR);

    // 4) projections -> bf16 (MFMA), then K/V fragment swizzles
    proj_mfma<<<N_LIG / 32, 256, 0, stream>>>(h_lig, wsb + SW_PQL, wsb + QL, 1);
    proj_mfma<<<N_LIG / 32, 256, 0, stream>>>(h_lig, wsb + SW_PKL, wsb + KL, 1);
    proj_mfma<<<N_LIG / 32, 256, 0, stream>>>(h_lig, wsb + SW_PVL, wsb + VL, 0);
    proj_mfma<<<N_REC / 32, 256, 0, stream>>>(h_rec, wsb + SW_PQR, wsb + QR, 1);
    proj_mfma<<<N_REC / 32, 256, 0, stream>>>(h_rec, wsb + SW_PKR, wsb + KR, 1);
    proj_mfma<<<N_REC / 32, 256, 0, stream>>>(h_rec, wsb + SW_PVR, wsb + VR, 0);
    kswz_kernel<<<N_LIG / 8, 256, 0, stream>>>(wsb + KL, wsb + KZL);
    kswz_kernel<<<N_REC / 8, 256, 0, stream>>>(wsb + KR, wsb + KZR);
    vswz_kernel<<<N_LIG / 32, 256, 0, stream>>>(wsb + VL, wsb + VZL);
    vswz_kernel<<<N_REC / 32, 256, 0, stream>>>(wsb + VR, wsb + VZR);

    // 5) MFMA flash attention, split-K + combine
    {
        dim3 gl(N_LIG / 64, SL);
        attn_mfma<<<gl, 256, 0, stream>>>(wsb + QL, wsb + KZR, wsb + VZR, mask,
                                          wsp + PO_, wsp + PM_, wsp + PL_,
                                          N_LIG, N_REC / SL, 0);
        attn_combine<<<N_LIG, 256, 0, stream>>>(
            wsp + PO_, wsp + PM_, wsp + PL_, wsb + CRL, N_LIG, SL);

        dim3 gr(N_REC / 64, SR);
        attn_mfma<<<gr, 256, 0, stream>>>(wsb + QR, wsb + KZL, wsb + VZL, mask,
                                          wsp + PO_, wsp + PM_, wsp + PL_,
                                          N_REC, N_LIG / SR, 1);
        attn_combine<<<N_REC, 256, 0, stream>>>(
            wsp + PO_, wsp + PM_, wsp + PL_, wsb + CRR, N_REC, SR);
    }

    // 6) coordinate outputs
    coords_fin<<<(N_LIG * 3 + 255) / 256, 256, 0, stream>>>(
        coords_lig, origc_lig, wsf + XSUML, wsf + CNTL, out + O_XL, N_LIG);
    coords_fin<<<(N_REC * 3 + 255) / 256, 256, 0, stream>>>(
        coords_rec, origc_rec, wsf + XSUMR, wsf + CNTR, out + O_XR, N_REC);

    // 7) node MFMA kernels
    node_mfma<<<N_LIG / 32, 256, 0, stream>>>(
        wsf + AGGRL, wsf + CNTL, wsb + CRL, orig_lig, h_lig,
        wsb + SW_NL1, nl_b1, wsb + SW_NL2, nl_b2, out + O_HL);
    node_mfma<<<N_REC / 32, 256, 0, stream>>>(
        wsf + AGGRR, wsf + CNTR, wsb + CRR, orig_rec, h_rec,
        wsb + SW_NR1, nr_b1, wsb + SW_NR2, nr_b2, out + O_HR);

    (void)in_sizes; (void)n_in; (void)out_size;
}

// Round 5
// 1678.561 us; speedup vs baseline: 1.2662x; 1.2662x over previous
//
#include <hip/hip_runtime.h>
#include <hip/hip_bf16.h>

// ---------------------------------------------------------------------------
// IEGMN layer, MI355X round-13: round-12 design (glds LDS double-buffered
// attention) with hardened address-space casts for global_load_lds
// (direct pointer addrspacecast, no integer round-trip).
//   zero_kernel  : zero atomic accumulators + CSR hist/cursors
//   hist_kernel  : per-dst edge histogram
//   scan_kernel  : single-block exclusive scan -> cursors + fp32 counts
//   scatter_kernel: dst-sorted edge permutation (elist)
//   wt_swz       : pack weights fp32[K][256] -> bf16 fragment-ordered blobs
//   edge_mfma    : gather + RBF + edge MLP + coords MLP, dst-sorted order;
//                  per-block segment reduction -> few atomics/block
//   proj_mfma    : q/k/v projections -> bf16 ws (MFMA)
//   kswz_kernel  : K [N][256] -> fragment-ordered blob (16B-chunk permutation)
//   vswz_kernel  : V [N][256] -> fragment-ordered blob (LDS-tiled transpose)
//   attn_mfma    : flash attention partial (split-K), MFMA 16x16x32 bf16,
//                  4 waves x 16 q-rows, LDS double-buffer + glds pipeline
//   attn_combine : merge splits -> bf16 cross features
//   coords_fin   : x_ev -> out (fp32)
//   node_mfma    : node MLP + skip -> out (fp32, MFMA)
// ---------------------------------------------------------------------------

#define N_LIG   4096
#define N_REC   16384
#define E_LIG_N 65536
#define E_REC_N 262144
#define HD      256
#define ORIGD   64
#define EFD     16
#define NSIG    15
#define EIN     543      // 2*HD + EFD + NSIG
#define XP      552      // edge sX pitch (bf16 elems), 544 used
#define XPN     584      // node sX pitch, 576 used
#define XPP     264      // proj sX pitch, 256 used
#define FP      264      // fp32 reuse pitch inside sX (floats)

typedef __bf16 bf16x8 __attribute__((ext_vector_type(8)));
typedef float  f32x4  __attribute__((ext_vector_type(4)));

__device__ __forceinline__ float lrelu(float x) { return x > 0.f ? x : 0.01f * x; }
__device__ __forceinline__ unsigned short f2bu(float f) {
    __hip_bfloat16 h = __float2bfloat16(f);
    return *reinterpret_cast<unsigned short*>(&h);
}

// Direct global->LDS async copy, 16B per lane. LDS dest = wave-uniform base
// + lane*16 (hardware); global src is per-lane. Direct addrspacecasts.
__device__ __forceinline__ void glds16(const void* g, void* l) {
    __builtin_amdgcn_global_load_lds(
        (const __attribute__((address_space(1))) void*)g,
        (__attribute__((address_space(3))) void*)l,
        16, 0, 0);
}

// Stage 16KB (one 32-key K or V tile) into LDS: 4 glds per thread.
__device__ __forceinline__ void stage16k(
    const __hip_bfloat16* g, unsigned short* l, int wave, int lane)
{
    #pragma unroll
    for (int i = 0; i < 4; ++i) {
        const __hip_bfloat16* gp = g + (size_t)(i * 256 + wave * 64 + lane) * 8;
        unsigned short* lp = l + (i * 2048 + wave * 512);   // wave-uniform base
        glds16(gp, lp);
    }
}

// ---------------------------------------------------------------------------
// Shared 32xKx256 GEMM core (reg double-buffered).
__device__ __forceinline__ void mfma_gemm(
    const unsigned short* sA, int pitch,
    const __hip_bfloat16* Wswz, int KS, int lane, f32x4 acc[2][4])
{
    const int col = lane & 15, quad = lane >> 4;
    const unsigned short* a0p = sA + (size_t)col * pitch + quad * 8;
    const unsigned short* a1p = sA + (size_t)(16 + col) * pitch + quad * 8;
    const __hip_bfloat16* wp = Wswz + lane * 8;
    bf16x8 bc[4], bn[4], a0c, a1c, a0n, a1n;
    #pragma unroll
    for (int nt = 0; nt < 4; ++nt)
        bc[nt] = *reinterpret_cast<const bf16x8*>(wp + (size_t)nt * KS * 512);
    a0c = *reinterpret_cast<const bf16x8*>(a0p);
    a1c = *reinterpret_cast<const bf16x8*>(a1p);
    for (int ks = 0; ks < KS; ++ks) {
        if (ks + 1 < KS) {
            #pragma unroll
            for (int nt = 0; nt < 4; ++nt)
                bn[nt] = *reinterpret_cast<const bf16x8*>(
                    wp + ((size_t)nt * KS + ks + 1) * 512);
            a0n = *reinterpret_cast<const bf16x8*>(a0p + (ks + 1) * 32);
            a1n = *reinterpret_cast<const bf16x8*>(a1p + (ks + 1) * 32);
        }
        #pragma unroll
        for (int nt = 0; nt < 4; ++nt) {
            acc[0][nt] = __builtin_amdgcn_mfma_f32_16x16x32_bf16(a0c, bc[nt], acc[0][nt], 0, 0, 0);
            acc[1][nt] = __builtin_amdgcn_mfma_f32_16x16x32_bf16(a1c, bc[nt], acc[1][nt], 0, 0, 0);
        }
        #pragma unroll
        for (int nt = 0; nt < 4; ++nt) bc[nt] = bn[nt];
        a0c = a0n; a1c = a1n;
    }
}

// ---------------------------------------------------------------------------
__global__ void zero_kernel(float* __restrict__ p, int n) {
    int i = blockIdx.x * 256 + threadIdx.x;
    if (i < n) p[i] = 0.f;
}

// ---------------------------------------------------------------------------
// CSR build: histogram -> scan -> scatter (dst-sorted edge permutation).
__global__ void hist_kernel(const int* __restrict__ dst, int* __restrict__ hist, int n) {
    int i = blockIdx.x * 256 + threadIdx.x;
    if (i < n) atomicAdd(&hist[dst[i]], 1);
}

__global__ __launch_bounds__(256) void scan_kernel(
    const int* __restrict__ hist, int* __restrict__ cur,
    float* __restrict__ cntf, int n)
{
    __shared__ int part[256];
    const int tid = threadIdx.x;
    const int per = n >> 8;            // n is 4096 or 16384
    const int base = tid * per;
    int s = 0;
    for (int i = 0; i < per; ++i) s += hist[base + i];
    part[tid] = s;
    __syncthreads();
    #pragma unroll
    for (int off = 1; off < 256; off <<= 1) {
        int v = (tid >= off) ? part[tid - off] : 0;
        __syncthreads();
        part[tid] += v;
        __syncthreads();
    }
    int run = part[tid] - s;           // exclusive prefix of this chunk
    for (int i = 0; i < per; ++i) {
        const int h = hist[base + i];
        cur[base + i]  = run;
        cntf[base + i] = (float)h;
        run += h;
    }
}

__global__ void scatter_kernel(const int* __restrict__ dst, int* __restrict__ cur,
                               int* __restrict__ elist, int n) {
    int i = blockIdx.x * 256 + threadIdx.x;
    if (i < n) { int p = atomicAdd(&cur[dst[i]], 1); elist[p] = i; }
}

// ---------------------------------------------------------------------------
__global__ void wt_swz(const float* __restrict__ src,
                       __hip_bfloat16* __restrict__ dst, int K, int KS) {
    const int g  = blockIdx.x / KS;
    const int ks = blockIdx.x % KS;
    for (int i = threadIdx.x; i < 512; i += 256) {
        const int lane = i >> 3, j = i & 7;
        const int n = g * 16 + (lane & 15);
        const int k = ks * 32 + (lane >> 4) * 8 + j;
        const float v = (k < K) ? src[(size_t)k * 256 + n] : 0.f;
        dst[((size_t)(g * KS + ks) * 64 + lane) * 8 + j] = __float2bfloat16(v);
    }
}

// ---------------------------------------------------------------------------
// K fragment swizzle: blob[((key/16)*8+s)*512 + lane*8 + j]
//   = K[(key/16)*16 + (lane&15)][s*32 + (lane>>4)*8 + j].  Pure 16B permute.
__global__ __launch_bounds__(256) void kswz_kernel(
    const __hip_bfloat16* __restrict__ K, __hip_bfloat16* __restrict__ blob)
{
    const int c = blockIdx.x * 256 + threadIdx.x;   // chunk id, N*32 total
    const int lane = c & 63;
    const int s    = (c >> 6) & 7;
    const int kt   = c >> 9;
    const __hip_bfloat16* src =
        K + (size_t)(kt * 16 + (lane & 15)) * HD + s * 32 + (lane >> 4) * 8;
    *reinterpret_cast<uint4*>(blob + (size_t)c * 8) =
        *reinterpret_cast<const uint4*>(src);
}

// ---------------------------------------------------------------------------
// V fragment swizzle: blob[((key32)*16+dt)*512 + lane*8 + j]
//   = V[key32*32 + (lane>>4)*8 + j][dt*16 + (lane&15)].  One 32-key tile/block.
__global__ __launch_bounds__(256) void vswz_kernel(
    const __hip_bfloat16* __restrict__ V, __hip_bfloat16* __restrict__ blob)
{
    __shared__ unsigned short s[32][264];
    const int jt  = blockIdx.x;
    const int tid = threadIdx.x;
    {   // stage V rows [32][256] (b128)
        const int row = tid >> 3;
        const int d0  = (tid & 7) * 32;
        const __hip_bfloat16* vp = V + (size_t)(jt * 32 + row) * HD + d0;
        #pragma unroll
        for (int i = 0; i < 4; ++i)
            *reinterpret_cast<uint4*>(&s[row][d0 + 8 * i]) =
                *reinterpret_cast<const uint4*>(vp + 8 * i);
    }
    __syncthreads();
    {
        const int w    = tid >> 6;
        const int lane = tid & 63;
        const int col  = lane & 15;
        const int quad = lane >> 4;
        #pragma unroll
        for (int i = 0; i < 4; ++i) {
            const int dt = w + i * 4;
            unsigned short tmp[8];
            #pragma unroll
            for (int j = 0; j < 8; ++j)
                tmp[j] = s[quad * 8 + j][dt * 16 + col];
            *reinterpret_cast<uint4*>(
                blob + ((size_t)(jt * 16 + dt) * 64 + lane) * 8) =
                *reinterpret_cast<uint4*>(tmp);
        }
    }
}

// ---------------------------------------------------------------------------
// Edge MFMA kernel: 32 edges/block, edges taken in dst-sorted order (elist).
__global__ __launch_bounds__(256, 4) void edge_mfma(
    const float* __restrict__ coords, const float* __restrict__ h,
    const float* __restrict__ ef,
    const int* __restrict__ src, const int* __restrict__ dst,
    const int* __restrict__ elist,
    const __hip_bfloat16* __restrict__ W1s, const float* __restrict__ b1,
    const __hip_bfloat16* __restrict__ W2s, const float* __restrict__ b2,
    const __hip_bfloat16* __restrict__ Wc1s, const float* __restrict__ bc1,
    const float* __restrict__ wc2v, const float* __restrict__ bc2,
    float* __restrict__ aggr, float* __restrict__ xsum)
{
    __shared__ unsigned short sX[32][XP];     // also reused as fp32 [32][FP]
    __shared__ float sXrel[32][3];
    __shared__ int   sDst[32];
    __shared__ int   sSrc[32];
    __shared__ int   sE[32];
    __shared__ float sRedW[4][32];
    __shared__ float sPv[32];

    const int tid  = threadIdx.x;
    const int lane = tid & 63;
    const int wave = tid >> 6;
    const int col  = lane & 15;
    const int quad = lane >> 4;
    const int e0   = blockIdx.x * 32;

    // ---- edge meta: permuted id, endpoints, x_rel, RBF ----
    if (tid < 32) {
        const int e = elist[e0 + tid];
        const int s = src[e], d = dst[e];
        sE[tid] = e; sSrc[tid] = s; sDst[tid] = d;
        float d2 = 0.f;
        #pragma unroll
        for (int c = 0; c < 3; ++c) {
            const float xr = coords[s * 3 + c] - coords[d * 3 + c];
            sXrel[tid][c] = xr;
            d2 += xr * xr;
        }
        float sig = 1.0f;
        #pragma unroll
        for (int si = 0; si < NSIG; ++si) {
            sX[tid][528 + si] = f2bu(__expf(-d2 / sig));
            sig *= 1.5f;
        }
        sX[tid][543] = 0;
    }
    __syncthreads();

    // ---- gather h[src], h[dst] ----
    for (int i = tid; i < 32 * 128; i += 256) {
        const int row = i >> 7, c4 = i & 127;
        const int node = (c4 < 64) ? sSrc[row] : sDst[row];
        const float4 v = *reinterpret_cast<const float4*>(
            &h[(size_t)node * HD + (c4 & 63) * 4]);
        ushort4 u = { f2bu(v.x), f2bu(v.y), f2bu(v.z), f2bu(v.w) };
        *reinterpret_cast<ushort4*>(&sX[row][c4 * 4]) = u;
    }
    // ---- gather edge features (permuted rows) ----
    if (tid < 128) {
        const int row = tid >> 2, c = tid & 3;
        const float4 v = *reinterpret_cast<const float4*>(
            &ef[(size_t)sE[row] * EFD + c * 4]);
        ushort4 u = { f2bu(v.x), f2bu(v.y), f2bu(v.z), f2bu(v.w) };
        *reinterpret_cast<ushort4*>(&sX[row][512 + c * 4]) = u;
    }
    __syncthreads();

    f32x4 acc[2][4];
    f32x4 macc[2][4];   // message accumulators, survive the coords GEMM

    // ---- GEMM1: [32 x 544] @ W1 -> hidden, lrelu ----
    #pragma unroll
    for (int nt = 0; nt < 4; ++nt) {
        const float bv = b1[wave * 64 + nt * 16 + col];
        acc[0][nt] = { bv, bv, bv, bv };
        acc[1][nt] = { bv, bv, bv, bv };
    }
    mfma_gemm(&sX[0][0], XP, W1s + (size_t)(wave * 4) * 17 * 512, 17, lane, acc);
    __syncthreads();
    #pragma unroll
    for (int mt = 0; mt < 2; ++mt)
        #pragma unroll
        for (int nt = 0; nt < 4; ++nt)
            #pragma unroll
            for (int r = 0; r < 4; ++r)
                sX[mt * 16 + quad * 4 + r][wave * 64 + nt * 16 + col] =
                    f2bu(lrelu(acc[mt][nt][r]));
    __syncthreads();

    // ---- GEMM2: hidden @ W2 -> msg (kept fp32 in macc) ----
    #pragma unroll
    for (int nt = 0; nt < 4; ++nt) {
        const float bv = b2[wave * 64 + nt * 16 + col];
        macc[0][nt] = { bv, bv, bv, bv };
        macc[1][nt] = { bv, bv, bv, bv };
    }
    mfma_gemm(&sX[0][0], XP, W2s + (size_t)(wave * 4) * 8 * 512, 8, lane, macc);
    __syncthreads();
    #pragma unroll
    for (int mt = 0; mt < 2; ++mt)
        #pragma unroll
        for (int nt = 0; nt < 4; ++nt)
            #pragma unroll
            for (int r = 0; r < 4; ++r)
                sX[mt * 16 + quad * 4 + r][wave * 64 + nt * 16 + col] =
                    f2bu(macc[mt][nt][r]);
    __syncthreads();

    // ---- GEMM3: msg @ Wc1 -> lrelu -> dot wc2 (per-edge scalar p) ----
    #pragma unroll
    for (int nt = 0; nt < 4; ++nt) {
        const float bv = bc1[wave * 64 + nt * 16 + col];
        acc[0][nt] = { bv, bv, bv, bv };
        acc[1][nt] = { bv, bv, bv, bv };
    }
    mfma_gemm(&sX[0][0], XP, Wc1s + (size_t)(wave * 4) * 8 * 512, 8, lane, acc);
    float w2l[4];
    #pragma unroll
    for (int nt = 0; nt < 4; ++nt) w2l[nt] = wc2v[wave * 64 + nt * 16 + col];
    #pragma unroll
    for (int mt = 0; mt < 2; ++mt) {
        float pr[4] = { 0.f, 0.f, 0.f, 0.f };
        #pragma unroll
        for (int nt = 0; nt < 4; ++nt)
            #pragma unroll
            for (int r = 0; r < 4; ++r)
                pr[r] += lrelu(acc[mt][nt][r]) * w2l[nt];
        #pragma unroll
        for (int r = 0; r < 4; ++r) {
            #pragma unroll
            for (int off = 1; off < 16; off <<= 1) pr[r] += __shfl_xor(pr[r], off);
        }
        if (col == 0)
            #pragma unroll
            for (int r = 0; r < 4; ++r)
                sRedW[wave][mt * 16 + quad * 4 + r] = pr[r];
    }
    __syncthreads();

    // ---- dump fp32 messages into LDS (reuse sX), gather p per edge ----
    float* sF = reinterpret_cast<float*>(&sX[0][0]);   // [32][FP] floats
    #pragma unroll
    for (int mt = 0; mt < 2; ++mt)
        #pragma unroll
        for (int nt = 0; nt < 4; ++nt)
            #pragma unroll
            for (int r = 0; r < 4; ++r)
                sF[(mt * 16 + quad * 4 + r) * FP + wave * 64 + nt * 16 + col] =
                    macc[mt][nt][r];
    if (tid < 32)
        sPv[tid] = sRedW[0][tid] + sRedW[1][tid] + sRedW[2][tid] + sRedW[3][tid]
                 + bc2[0];
    __syncthreads();

    // ---- segmented flush: one atomic per (distinct dst x column) ----
    {
        const int c = tid;               // 256 threads = 256 columns
        float av = 0.f;
        int dprev = sDst[0];
        for (int row = 0; row < 32; ++row) {
            const int d = sDst[row];     // uniform across block -> no divergence
            if (d != dprev) {
                atomicAdd(&aggr[(size_t)dprev * HD + c], av);
                av = 0.f; dprev = d;
            }
            av += sF[row * FP + c];
        }
        atomicAdd(&aggr[(size_t)dprev * HD + c], av);
    }
    if (tid < 3) {
        const int c = tid;
        float av = 0.f;
        int dprev = sDst[0];
        for (int row = 0; row < 32; ++row) {
            const int d = sDst[row];
            if (d != dprev) {
                atomicAdd(&xsum[(size_t)dprev * 3 + c], av);
                av = 0.f; dprev = d;
            }
            av += sXrel[row][c] * sPv[row];
        }
        atomicAdd(&xsum[(size_t)dprev * 3 + c], av);
    }
}

// ---------------------------------------------------------------------------
// Node MFMA kernel: 32 nodes/block (unchanged).
__global__ __launch_bounds__(256, 4) void node_mfma(
    const float* __restrict__ aggr, const float* __restrict__ cnt,
    const __hip_bfloat16* __restrict__ cross, const float* __restrict__ orig,
    const float* __restrict__ hfeat,
    const __hip_bfloat16* __restrict__ WN1s, const float* __restrict__ b1,
    const __hip_bfloat16* __restrict__ WN2s, const float* __restrict__ b2,
    float* __restrict__ out)
{
    __shared__ unsigned short sXn[32][XPN];
    __shared__ float sInv[32];

    const int tid  = threadIdx.x;
    const int lane = tid & 63;
    const int wave = tid >> 6;
    const int col  = lane & 15;
    const int quad = lane >> 4;
    const int r0   = blockIdx.x * 32;

    if (tid < 32) sInv[tid] = 1.f / fmaxf(cnt[r0 + tid], 1.f);
    __syncthreads();

    for (int i = tid; i < 32 * 64; i += 256) {
        const int row = i >> 6, c4 = i & 63;
        const float inv = sInv[row];
        const float4 v = *reinterpret_cast<const float4*>(
            &aggr[(size_t)(r0 + row) * HD + c4 * 4]);
        ushort4 u = { f2bu(v.x * inv), f2bu(v.y * inv), f2bu(v.z * inv), f2bu(v.w * inv) };
        *reinterpret_cast<ushort4*>(&sXn[row][c4 * 4]) = u;
    }
    for (int i = tid; i < 32 * 64; i += 256) {
        const int row = i >> 6, c4 = i & 63;
        const ushort4 u = *reinterpret_cast<const ushort4*>(
            &cross[(size_t)(r0 + row) * HD + c4 * 4]);
        *reinterpret_cast<ushort4*>(&sXn[row][256 + c4 * 4]) = u;
    }
    for (int i = tid; i < 32 * 16; i += 256) {
        const int row = i >> 4, c4 = i & 15;
        const float4 v = *reinterpret_cast<const float4*>(
            &orig[(size_t)(r0 + row) * ORIGD + c4 * 4]);
        ushort4 u = { f2bu(v.x), f2bu(v.y), f2bu(v.z), f2bu(v.w) };
        *reinterpret_cast<ushort4*>(&sXn[row][512 + c4 * 4]) = u;
    }
    __syncthreads();

    f32x4 acc[2][4];

    #pragma unroll
    for (int nt = 0; nt < 4; ++nt) {
        const float bv = b1[wave * 64 + nt * 16 + col];
        acc[0][nt] = { bv, bv, bv, bv };
        acc[1][nt] = { bv, bv, bv, bv };
    }
    mfma_gemm(&sXn[0][0], XPN, WN1s + (size_t)(wave * 4) * 18 * 512, 18, lane, acc);
    __syncthreads();
    #pragma unroll
    for (int mt = 0; mt < 2; ++mt)
        #pragma unroll
        for (int nt = 0; nt < 4; ++nt)
            #pragma unroll
            for (int r = 0; r < 4; ++r)
                sXn[mt * 16 + quad * 4 + r][wave * 64 + nt * 16 + col] =
                    f2bu(lrelu(acc[mt][nt][r]));
    __syncthreads();

    #pragma unroll
    for (int nt = 0; nt < 4; ++nt) {
        const float bv = b2[wave * 64 + nt * 16 + col];
        acc[0][nt] = { bv, bv, bv, bv };
        acc[1][nt] = { bv, bv, bv, bv };
    }
    mfma_gemm(&sXn[0][0], XPN, WN2s + (size_t)(wave * 4) * 8 * 512, 8, lane, acc);
    #pragma unroll
    for (int mt = 0; mt < 2; ++mt)
        #pragma unroll
        for (int nt = 0; nt < 4; ++nt)
            #pragma unroll
            for (int r = 0; r < 4; ++r) {
                const int g = r0 + mt * 16 + quad * 4 + r;
                const int n = wave * 64 + nt * 16 + col;
                out[(size_t)g * HD + n] =
                    0.5f * acc[mt][nt][r] + 0.5f * hfeat[(size_t)g * HD + n];
            }
}

// ---------------------------------------------------------------------------
// Projection MFMA (unchanged).
__global__ __launch_bounds__(256, 4) void proj_mfma(
    const float* __restrict__ X, const __hip_bfloat16* __restrict__ Ws,
    __hip_bfloat16* __restrict__ out, int applyLrelu)
{
    __shared__ unsigned short sXp[32][XPP];
    const int tid  = threadIdx.x;
    const int lane = tid & 63;
    const int wave = tid >> 6;
    const int col  = lane & 15;
    const int quad = lane >> 4;
    const int r0   = blockIdx.x * 32;

    for (int i = tid; i < 32 * 64; i += 256) {
        const int row = i >> 6, c4 = i & 63;
        const float4 v = *reinterpret_cast<const float4*>(
            &X[(size_t)(r0 + row) * HD + c4 * 4]);
        ushort4 u = { f2bu(v.x), f2bu(v.y), f2bu(v.z), f2bu(v.w) };
        *reinterpret_cast<ushort4*>(&sXp[row][c4 * 4]) = u;
    }
    __syncthreads();

    f32x4 acc[2][4];
    #pragma unroll
    for (int nt = 0; nt < 4; ++nt) {
        acc[0][nt] = { 0.f, 0.f, 0.f, 0.f };
        acc[1][nt] = { 0.f, 0.f, 0.f, 0.f };
    }
    mfma_gemm(&sXp[0][0], XPP, Ws + (size_t)(wave * 4) * 8 * 512, 8, lane, acc);
    #pragma unroll
    for (int mt = 0; mt < 2; ++mt)
        #pragma unroll
        for (int nt = 0; nt < 4; ++nt)
            #pragma unroll
            for (int r = 0; r < 4; ++r) {
                float v = acc[mt][nt][r];
                if (applyLrelu) v = lrelu(v);
                out[(size_t)(r0 + mt * 16 + quad * 4 + r) * HD +
                    wave * 64 + nt * 16 + col] = __float2bfloat16(v);
            }
}

// ---------------------------------------------------------------------------
// Attention helpers.
__device__ __forceinline__ void load_mask(
    const float* __restrict__ maskG, int transposed, int R0, int j0,
    int wave, int quad, int col, float mv[2][4])
{
    if (!transposed) {
        #pragma unroll
        for (int t = 0; t < 2; ++t)
            #pragma unroll
            for (int r = 0; r < 4; ++r)
                mv[t][r] = maskG[(size_t)(R0 + wave * 16 + quad * 4 + r) * N_REC
                                 + j0 + col + 16 * t];
    } else {
        #pragma unroll
        for (int t = 0; t < 2; ++t)
            #pragma unroll
            for (int r = 0; r < 4; ++r)
                mv[t][r] = maskG[(size_t)(j0 + col + 16 * t) * N_REC
                                 + R0 + wave * 16 + quad * 4 + r];
    }
}

__device__ __forceinline__ void attn_tile(
    const unsigned short* sK, const unsigned short* sV,
    unsigned short (*sPw)[40], const bf16x8 qf[8], const float mv[2][4],
    int lane, int col, int quad, f32x4 o[16], float m[4], float l[4])
{
    // ---- S = Q K^T ----
    f32x4 sacc[2];
    sacc[0][0]=0.f; sacc[0][1]=0.f; sacc[0][2]=0.f; sacc[0][3]=0.f;
    sacc[1][0]=0.f; sacc[1][1]=0.f; sacc[1][2]=0.f; sacc[1][3]=0.f;
    #pragma unroll
    for (int t = 0; t < 2; ++t) {
        #pragma unroll
        for (int s = 0; s < 8; ++s) {
            bf16x8 kf = *reinterpret_cast<const bf16x8*>(
                &sK[(t * 8 + s) * 512 + lane * 8]);
            sacc[t] = __builtin_amdgcn_mfma_f32_16x16x32_bf16(qf[s], kf, sacc[t], 0, 0, 0);
        }
    }

    // ---- online softmax (mask from registers) ----
    float a[2][4];
    #pragma unroll
    for (int t = 0; t < 2; ++t)
        #pragma unroll
        for (int r = 0; r < 4; ++r)
            a[t][r] = mv[t][r] * sacc[t][r] - 1000.f * (1.f - mv[t][r]);
    #pragma unroll
    for (int r = 0; r < 4; ++r) {
        float mx = fmaxf(a[0][r], a[1][r]);
        #pragma unroll
        for (int off = 1; off < 16; off <<= 1)
            mx = fmaxf(mx, __shfl_xor(mx, off));
        const float mn = fmaxf(m[r], mx);
        const float c  = __expf(m[r] - mn);
        m[r] = mn;
        const float p0 = __expf(a[0][r] - mn);
        const float p1 = __expf(a[1][r] - mn);
        sPw[quad * 4 + r][col]      = f2bu(p0);
        sPw[quad * 4 + r][col + 16] = f2bu(p1);
        float ps = p0 + p1;
        #pragma unroll
        for (int off = 1; off < 16; off <<= 1)
            ps += __shfl_xor(ps, off);
        l[r] = l[r] * c + ps;
        #pragma unroll
        for (int dt = 0; dt < 16; ++dt) o[dt][r] *= c;
    }

    // ---- O += P V ----
    bf16x8 pf = *reinterpret_cast<const bf16x8*>(&sPw[col][quad * 8]);
    #pragma unroll
    for (int dt = 0; dt < 16; ++dt) {
        bf16x8 vf = *reinterpret_cast<const bf16x8*>(&sV[dt * 512 + lane * 8]);
        o[dt] = __builtin_amdgcn_mfma_f32_16x16x32_bf16(pf, vf, o[dt], 0, 0, 0);
    }
}

// ---------------------------------------------------------------------------
// MFMA flash attention partial. 64 q-rows/block (4 waves x 16), 32-key tiles.
// K/V double-buffered in LDS via global_load_lds (no VGPR round-trip, no
// spill); masks prefetched one tile ahead into alternating reg sets.
// Per phase: vmcnt(0)+s_barrier (tile ready, prev buffer free), issue next
// tile's glds+mask loads, compute current tile. Loads fly across the whole
// tile's MFMA+softmax.
__global__ __launch_bounds__(256) void attn_mfma(
    const __hip_bfloat16* __restrict__ Qb, const __hip_bfloat16* __restrict__ Kz,
    const __hip_bfloat16* __restrict__ Vz, const float* __restrict__ maskG,
    float* __restrict__ PO, float* __restrict__ PM, float* __restrict__ PL,
    int M, int chunkKeys, int transposed)
{
    __shared__ unsigned short sKb[2][8192];   // 2 x 16 KB
    __shared__ unsigned short sVb[2][8192];   // 2 x 16 KB
    __shared__ unsigned short sP[4][16][40];

    const int tid  = threadIdx.x;
    const int lane = tid & 63;
    const int wave = tid >> 6;
    const int col  = lane & 15;
    const int quad = lane >> 4;
    const int R0   = blockIdx.x * 64;
    const int split = blockIdx.y;
    const int jbase = split * chunkKeys;

    bf16x8 qf[8];
    {
        const __hip_bfloat16* qp =
            Qb + (size_t)(R0 + wave * 16 + col) * HD + quad * 8;
        #pragma unroll
        for (int s = 0; s < 8; ++s)
            qf[s] = *reinterpret_cast<const bf16x8*>(qp + 32 * s);
    }

    f32x4 o[16];
    #pragma unroll
    for (int dt = 0; dt < 16; ++dt) { o[dt][0]=0.f; o[dt][1]=0.f; o[dt][2]=0.f; o[dt][3]=0.f; }
    float m[4], l[4];
    #pragma unroll
    for (int r = 0; r < 4; ++r) { m[r] = -INFINITY; l[r] = 0.f; }

    float mvA[2][4], mvB[2][4];

    // ---- prologue: tile 0 -> buf0 + mvA ----
    stage16k(Kz + (size_t)jbase * 256, &sKb[0][0], wave, lane);
    stage16k(Vz + (size_t)jbase * 256, &sVb[0][0], wave, lane);
    load_mask(maskG, transposed, R0, jbase, wave, quad, col, mvA);

    for (int jt = 0; jt < chunkKeys; jt += 64) {
        // ===== phase A: compute tile jt (buf0, mvA); stage jt+32 =====
        asm volatile("s_waitcnt vmcnt(0)" ::: "memory");
        __builtin_amdgcn_s_barrier();
        __builtin_amdgcn_sched_barrier(0);
        stage16k(Kz + (size_t)(jbase + jt + 32) * 256, &sKb[1][0], wave, lane);
        stage16k(Vz + (size_t)(jbase + jt + 32) * 256, &sVb[1][0], wave, lane);
        load_mask(maskG, transposed, R0, jbase + jt + 32, wave, quad, col, mvB);
        __builtin_amdgcn_sched_barrier(0);
        attn_tile(&sKb[0][0], &sVb[0][0], sP[wave], qf, mvA,
                  lane, col, quad, o, m, l);

        // ===== phase B: compute tile jt+32 (buf1, mvB); stage jt+64 =====
        asm volatile("s_waitcnt vmcnt(0)" ::: "memory");
        __builtin_amdgcn_s_barrier();
        __builtin_amdgcn_sched_barrier(0);
        if (jt + 64 < chunkKeys) {
            stage16k(Kz + (size_t)(jbase + jt + 64) * 256, &sKb[0][0], wave, lane);
            stage16k(Vz + (size_t)(jbase + jt + 64) * 256, &sVb[0][0], wave, lane);
            load_mask(maskG, transposed, R0, jbase + jt + 64, wave, quad, col, mvA);
        }
        __builtin_amdgcn_sched_barrier(0);
        attn_tile(&sKb[1][0], &sVb[1][0], sP[wave], qf, mvB,
                  lane, col, quad, o, m, l);
    }

    #pragma unroll
    for (int dt = 0; dt < 16; ++dt)
        #pragma unroll
        for (int r = 0; r < 4; ++r) {
            const int row = R0 + wave * 16 + quad * 4 + r;
            PO[((size_t)split * M + row) * HD + dt * 16 + col] = o[dt][r];
        }
    if (col == 0) {
        #pragma unroll
        for (int r = 0; r < 4; ++r) {
            const int row = R0 + wave * 16 + quad * 4 + r;
            PM[(size_t)split * M + row] = m[r];
            PL[(size_t)split * M + row] = l[r];
        }
    }
}

// ---------------------------------------------------------------------------
__global__ void attn_combine(
    const float* __restrict__ PO, const float* __restrict__ PM,
    const float* __restrict__ PL, __hip_bfloat16* __restrict__ Out,
    int M, int nchunks)
{
    const int idx = blockIdx.x * 256 + threadIdx.x;
    const int row = idx >> 8;
    float mmax = -INFINITY;
    for (int c = 0; c < nchunks; ++c) mmax = fmaxf(mmax, PM[(size_t)c * M + row]);
    float denom = 0.f, acc = 0.f;
    for (int c = 0; c < nchunks; ++c) {
        const float w = __expf(PM[(size_t)c * M + row] - mmax);
        denom += PL[(size_t)c * M + row] * w;
        acc   += PO[(size_t)c * M * HD + idx] * w;
    }
    Out[idx] = __float2bfloat16(acc / denom);
}

// ---------------------------------------------------------------------------
__global__ void coords_fin(
    const float* __restrict__ coords, const float* __restrict__ origc,
    const float* __restrict__ xsum, const float* __restrict__ cnt,
    float* __restrict__ out, int n)
{
    const int i = blockIdx.x * 256 + threadIdx.x;
    if (i >= n * 3) return;
    const int node = i / 3;
    const float inv = 1.f / fmaxf(cnt[node], 1.f);
    out[i] = 0.25f * origc[i] + 0.75f * coords[i] + xsum[i] * inv;
}

// ---------------------------------------------------------------------------
extern "C" void kernel_launch(void* const* d_in, const int* in_sizes, int n_in,
                              void* d_out, int out_size, void* d_ws, size_t ws_size,
                              hipStream_t stream)
{
    const float* coords_lig = (const float*)d_in[0];
    const float* h_lig      = (const float*)d_in[1];
    const float* orig_lig   = (const float*)d_in[2];
    const float* origc_lig  = (const float*)d_in[3];
    const float* coords_rec = (const float*)d_in[4];
    const float* h_rec      = (const float*)d_in[5];
    const float* orig_rec   = (const float*)d_in[6];
    const float* origc_rec  = (const float*)d_in[7];
    const float* mask       = (const float*)d_in[8];
    const float* lig_ef     = (const float*)d_in[9];
    const float* rec_ef     = (const float*)d_in[10];
    const int* lig_src = (const int*)d_in[11];
    const int* lig_dst = (const int*)d_in[12];
    const int* rec_src = (const int*)d_in[13];
    const int* rec_dst = (const int*)d_in[14];
    const float* le_w1 = (const float*)d_in[15];
    const float* le_b1 = (const float*)d_in[16];
    const float* le_w2 = (const float*)d_in[17];
    const float* le_b2 = (const float*)d_in[18];
    const float* re_w1 = (const float*)d_in[19];
    const float* re_b1 = (const float*)d_in[20];
    const float* re_w2 = (const float*)d_in[21];
    const float* re_b2 = (const float*)d_in[22];
    const float* aql_w = (const float*)d_in[23];
    const float* akl_w = (const float*)d_in[24];
    const float* avl_w = (const float*)d_in[25];
    const float* aqr_w = (const float*)d_in[26];
    const float* akr_w = (const float*)d_in[27];
    const float* avr_w = (const float*)d_in[28];
    const float* nl_w1 = (const float*)d_in[29];
    const float* nl_b1 = (const float*)d_in[30];
    const float* nl_w2 = (const float*)d_in[31];
    const float* nl_b2 = (const float*)d_in[32];
    const float* nr_w1 = (const float*)d_in[33];
    const float* nr_b1 = (const float*)d_in[34];
    const float* nr_w2 = (const float*)d_in[35];
    const float* nr_b2 = (const float*)d_in[36];
    const float* cl_w1 = (const float*)d_in[37];
    const float* cl_b1 = (const float*)d_in[38];
    const float* cl_w2 = (const float*)d_in[39];
    const float* cl_b2 = (const float*)d_in[40];
    const float* cr_w1 = (const float*)d_in[41];
    const float* cr_b1 = (const float*)d_in[42];
    const float* cr_w2 = (const float*)d_in[43];
    const float* cr_b2 = (const float*)d_in[44];

    float* out = (float*)d_out;
    float* wsf = (float*)d_ws;

    // ---- fp32 accumulator + CSR zone ----
    const size_t AGGRL = 0;
    const size_t AGGRR = AGGRL + (size_t)N_LIG * HD;
    const size_t CNTL  = AGGRR + (size_t)N_REC * HD;
    const size_t CNTR  = CNTL + N_LIG;
    const size_t XSUML = CNTR + N_REC;
    const size_t XSUMR = XSUML + (size_t)N_LIG * 3;
    const size_t HISTL = XSUMR + (size_t)N_REC * 3;
    const size_t CURL  = HISTL + N_LIG;
    const size_t HISTR = CURL + N_LIG;
    const size_t CURR  = HISTR + N_REC;
    const size_t ZEND  = CURR + N_REC;          // zeroed through here
    const size_t ELISTL = ZEND;                 // not zeroed
    const size_t ELISTR = ELISTL + E_LIG_N;
    const size_t FEND   = ELISTR + E_REC_N;

    // ---- bf16 zone ----
    __hip_bfloat16* wsb = (__hip_bfloat16*)(wsf + FEND);
    const size_t QL  = 0;
    const size_t KL  = QL + (size_t)N_LIG * HD;
    const size_t VL  = KL + (size_t)N_LIG * HD;
    const size_t QR  = VL + (size_t)N_LIG * HD;
    const size_t KR  = QR + (size_t)N_REC * HD;
    const size_t VR  = KR + (size_t)N_REC * HD;
    const size_t CRL = VR + (size_t)N_REC * HD;
    const size_t CRR = CRL + (size_t)N_LIG * HD;
    const size_t KZL = CRR + (size_t)N_REC * HD;          // K swizzled lig
    const size_t VZL = KZL + (size_t)N_LIG * HD;          // V swizzled lig
    const size_t KZR = VZL + (size_t)N_LIG * HD;          // K swizzled rec
    const size_t VZR = KZR + (size_t)N_REC * HD;          // V swizzled rec
    const size_t EW1SZ = (size_t)16 * 17 * 512;
    const size_t KW256 = (size_t)16 * 8 * 512;
    const size_t NW1SZ = (size_t)16 * 18 * 512;
    const size_t SW_EL1 = VZR + (size_t)N_REC * HD;
    const size_t SW_EL2 = SW_EL1 + EW1SZ;
    const size_t SW_EC1 = SW_EL2 + KW256;
    const size_t SW_NL1 = SW_EC1 + KW256;
    const size_t SW_NL2 = SW_NL1 + NW1SZ;
    const size_t SW_ER1 = SW_NL2 + KW256;
    const size_t SW_ER2 = SW_ER1 + EW1SZ;
    const size_t SW_EC1R = SW_ER2 + KW256;
    const size_t SW_NR1 = SW_EC1R + KW256;
    const size_t SW_NR2 = SW_NR1 + NW1SZ;
    const size_t SW_PQL = SW_NR2 + KW256;
    const size_t SW_PKL = SW_PQL + KW256;
    const size_t SW_PVL = SW_PKL + KW256;
    const size_t SW_PQR = SW_PVL + KW256;
    const size_t SW_PKR = SW_PQR + KW256;
    const size_t SW_PVR = SW_PKR + KW256;
    const size_t BF_END = SW_PVR + KW256;

    // ---- split-K partial zone (fp32), dynamic splits ----
    float* wsp = (float*)(wsb + ((BF_END + 1) & ~(size_t)1));
    const size_t baseBytes = (size_t)((char*)wsp - (char*)d_ws);
    int SL = 16, SR = 4;
    {
        const size_t poElems16 = (size_t)16 * N_LIG * HD;
        const size_t need16 = baseBytes +
            (poElems16 + 2 * (size_t)16 * N_LIG) * sizeof(float);
        if (ws_size < need16) { SL = 8; SR = 2; }
    }
    const size_t PO_ = 0;
    const size_t PM_ = PO_ + (size_t)SL * N_LIG * HD;
    const size_t PL_ = PM_ + (size_t)SL * N_LIG;

    const size_t O_XL = 0;
    const size_t O_HL = O_XL + (size_t)N_LIG * 3;
    const size_t O_XR = O_HL + (size_t)N_LIG * HD;
    const size_t O_HR = O_XR + (size_t)N_REC * 3;

    // 1) zero atomic accumulators + CSR hist/cursors
    zero_kernel<<<((int)ZEND + 255) / 256, 256, 0, stream>>>(wsf, (int)ZEND);

    // 1b) CSR build: dst-sorted edge permutations (also produces fp32 counts)
    hist_kernel<<<E_LIG_N / 256, 256, 0, stream>>>(lig_dst, (int*)(wsf + HISTL), E_LIG_N);
    hist_kernel<<<E_REC_N / 256, 256, 0, stream>>>(rec_dst, (int*)(wsf + HISTR), E_REC_N);
    scan_kernel<<<1, 256, 0, stream>>>((int*)(wsf + HISTL), (int*)(wsf + CURL),
                                       wsf + CNTL, N_LIG);
    scan_kernel<<<1, 256, 0, stream>>>((int*)(wsf + HISTR), (int*)(wsf + CURR),
                                       wsf + CNTR, N_REC);
    scatter_kernel<<<E_LIG_N / 256, 256, 0, stream>>>(
        lig_dst, (int*)(wsf + CURL), (int*)(wsf + ELISTL), E_LIG_N);
    scatter_kernel<<<E_REC_N / 256, 256, 0, stream>>>(
        rec_dst, (int*)(wsf + CURR), (int*)(wsf + ELISTR), E_REC_N);

    // 2) weight swizzles
    wt_swz<<<16 * 17, 256, 0, stream>>>(le_w1, wsb + SW_EL1, EIN, 17);
    wt_swz<<<16 * 8,  256, 0, stream>>>(le_w2, wsb + SW_EL2, 256, 8);
    wt_swz<<<16 * 8,  256, 0, stream>>>(cl_w1, wsb + SW_EC1, 256, 8);
    wt_swz<<<16 * 18, 256, 0, stream>>>(nl_w1, wsb + SW_NL1, 576, 18);
    wt_swz<<<16 * 8,  256, 0, stream>>>(nl_w2, wsb + SW_NL2, 256, 8);
    wt_swz<<<16 * 17, 256, 0, stream>>>(re_w1, wsb + SW_ER1, EIN, 17);
    wt_swz<<<16 * 8,  256, 0, stream>>>(re_w2, wsb + SW_ER2, 256, 8);
    wt_swz<<<16 * 8,  256, 0, stream>>>(cr_w1, wsb + SW_EC1R, 256, 8);
    wt_swz<<<16 * 18, 256, 0, stream>>>(nr_w1, wsb + SW_NR1, 576, 18);
    wt_swz<<<16 * 8,  256, 0, stream>>>(nr_w2, wsb + SW_NR2, 256, 8);
    wt_swz<<<16 * 8,  256, 0, stream>>>(aql_w, wsb + SW_PQL, 256, 8);
    wt_swz<<<16 * 8,  256, 0, stream>>>(akl_w, wsb + SW_PKL, 256, 8);
    wt_swz<<<16 * 8,  256, 0, stream>>>(avl_w, wsb + SW_PVL, 256, 8);
    wt_swz<<<16 * 8,  256, 0, stream>>>(aqr_w, wsb + SW_PQR, 256, 8);
    wt_swz<<<16 * 8,  256, 0, stream>>>(akr_w, wsb + SW_PKR, 256, 8);
    wt_swz<<<16 * 8,  256, 0, stream>>>(avr_w, wsb + SW_PVR, 256, 8);

    // 3) edge MFMA kernels (dst-sorted order, segmented atomics)
    edge_mfma<<<E_LIG_N / 32, 256, 0, stream>>>(
        coords_lig, h_lig, lig_ef, lig_src, lig_dst, (const int*)(wsf + ELISTL),
        wsb + SW_EL1, le_b1, wsb + SW_EL2, le_b2, wsb + SW_EC1, cl_b1, cl_w2, cl_b2,
        wsf + AGGRL, wsf + XSUML);
    edge_mfma<<<E_REC_N / 32, 256, 0, stream>>>(
        coords_rec, h_rec, rec_ef, rec_src, rec_dst, (const int*)(wsf + ELISTR),
        wsb + SW_ER1, re_b1, wsb + SW_ER2, re_b2, wsb + SW_EC1R, cr_b1, cr_w2, cr_b2,
        wsf + AGGRR, wsf + XSUMR);

    // 4) projections -> bf16 (MFMA), then K/V fragment swizzles
    proj_mfma<<<N_LIG / 32, 256, 0, stream>>>(h_lig, wsb + SW_PQL, wsb + QL, 1);
    proj_mfma<<<N_LIG / 32, 256, 0, stream>>>(h_lig, wsb + SW_PKL, wsb + KL, 1);
    proj_mfma<<<N_LIG / 32, 256, 0, stream>>>(h_lig, wsb + SW_PVL, wsb + VL, 0);
    proj_mfma<<<N_REC / 32, 256, 0, stream>>>(h_rec, wsb + SW_PQR, wsb + QR, 1);
    proj_mfma<<<N_REC / 32, 256, 0, stream>>>(h_rec, wsb + SW_PKR, wsb + KR, 1);
    proj_mfma<<<N_REC / 32, 256, 0, stream>>>(h_rec, wsb + SW_PVR, wsb + VR, 0);
    kswz_kernel<<<N_LIG / 8, 256, 0, stream>>>(wsb + KL, wsb + KZL);
    kswz_kernel<<<N_REC / 8, 256, 0, stream>>>(wsb + KR, wsb + KZR);
    vswz_kernel<<<N_LIG / 32, 256, 0, stream>>>(wsb + VL, wsb + VZL);
    vswz_kernel<<<N_REC / 32, 256, 0, stream>>>(wsb + VR, wsb + VZR);

    // 5) MFMA flash attention, split-K + combine
    {
        dim3 gl(N_LIG / 64, SL);
        attn_mfma<<<gl, 256, 0, stream>>>(wsb + QL, wsb + KZR, wsb + VZR, mask,
                                          wsp + PO_, wsp + PM_, wsp + PL_,
                                          N_LIG, N_REC / SL, 0);
        attn_combine<<<N_LIG, 256, 0, stream>>>(
            wsp + PO_, wsp + PM_, wsp + PL_, wsb + CRL, N_LIG, SL);

        dim3 gr(N_REC / 64, SR);
        attn_mfma<<<gr, 256, 0, stream>>>(wsb + QR, wsb + KZL, wsb + VZL, mask,
                                          wsp + PO_, wsp + PM_, wsp + PL_,
                                          N_REC, N_LIG / SR, 1);
        attn_combine<<<N_REC, 256, 0, stream>>>(
            wsp + PO_, wsp + PM_, wsp + PL_, wsb + CRR, N_REC, SR);
    }

    // 6) coordinate outputs
    coords_fin<<<(N_LIG * 3 + 255) / 256, 256, 0, stream>>>(
        coords_lig, origc_lig, wsf + XSUML, wsf + CNTL, out + O_XL, N_LIG);
    coords_fin<<<(N_REC * 3 + 255) / 256, 256, 0, stream>>>(
        coords_rec, origc_rec, wsf + XSUMR, wsf + CNTR, out + O_XR, N_REC);

    // 7) node MFMA kernels
    node_mfma<<<N_LIG / 32, 256, 0, stream>>>(
        wsf + AGGRL, wsf + CNTL, wsb + CRL, orig_lig, h_lig,
        wsb + SW_NL1, nl_b1, wsb + SW_NL2, nl_b2, out + O_HL);
    node_mfma<<<N_REC / 32, 256, 0, stream>>>(
        wsf + AGGRR, wsf + CNTR, wsb + CRR, orig_rec, h_rec,
        wsb + SW_NR1, nr_b1, wsb + SW_NR2, nr_b2, out + O_HR);

    (void)in_sizes; (void)n_in; (void)out_size;
}

// Round 6
// 1314.018 us; speedup vs baseline: 1.6175x; 1.2774x over previous
//
#include <hip/hip_runtime.h>
#include <hip/hip_bf16.h>

// ---------------------------------------------------------------------------
// IEGMN layer, MI355X round-14: attention widened to 8 waves / 128 q-rows
// per block (2x compute per staged tile, 8 waves/CU even at 1 block/CU)
// + defer-max softmax (skip rescale unless local max grows past THR=8)
// + deferred l-reduction (per-lane partials, one reduce at end).
//   zero_kernel  : zero atomic accumulators + CSR hist/cursors
//   hist_kernel  : per-dst edge histogram
//   scan_kernel  : single-block exclusive scan -> cursors + fp32 counts
//   scatter_kernel: dst-sorted edge permutation (elist)
//   wt_swz       : pack weights fp32[K][256] -> bf16 fragment-ordered blobs
//   edge_mfma    : gather + RBF + edge MLP + coords MLP, dst-sorted order;
//                  per-block segment reduction -> few atomics/block
//   proj_mfma    : q/k/v projections -> bf16 ws (MFMA)
//   kswz_kernel  : K [N][256] -> fragment-ordered blob (16B-chunk permutation)
//   vswz_kernel  : V [N][256] -> fragment-ordered blob (LDS-tiled transpose)
//   attn_mfma    : flash attention partial (split-K), MFMA 16x16x32 bf16,
//                  8 waves x 16 q-rows, LDS double-buffer + glds pipeline
//   attn_combine : merge splits -> bf16 cross features
//   coords_fin   : x_ev -> out (fp32)
//   node_mfma    : node MLP + skip -> out (fp32, MFMA)
// ---------------------------------------------------------------------------

#define N_LIG   4096
#define N_REC   16384
#define E_LIG_N 65536
#define E_REC_N 262144
#define HD      256
#define ORIGD   64
#define EFD     16
#define NSIG    15
#define EIN     543      // 2*HD + EFD + NSIG
#define XP      552      // edge sX pitch (bf16 elems), 544 used
#define XPN     584      // node sX pitch, 576 used
#define XPP     264      // proj sX pitch, 256 used
#define FP      264      // fp32 reuse pitch inside sX (floats)

typedef __bf16 bf16x8 __attribute__((ext_vector_type(8)));
typedef float  f32x4  __attribute__((ext_vector_type(4)));

__device__ __forceinline__ float lrelu(float x) { return x > 0.f ? x : 0.01f * x; }
__device__ __forceinline__ unsigned short f2bu(float f) {
    __hip_bfloat16 h = __float2bfloat16(f);
    return *reinterpret_cast<unsigned short*>(&h);
}

// Direct global->LDS async copy, 16B per lane. LDS dest = wave-uniform base
// + lane*16 (hardware); global src is per-lane. Direct addrspacecasts.
__device__ __forceinline__ void glds16(const void* g, void* l) {
    __builtin_amdgcn_global_load_lds(
        (const __attribute__((address_space(1))) void*)g,
        (__attribute__((address_space(3))) void*)l,
        16, 0, 0);
}

// Stage 16KB (one 32-key K or V tile) into LDS with 512 threads (8 waves):
// 2 glds per thread.
__device__ __forceinline__ void stage_tile(
    const __hip_bfloat16* g, unsigned short* l, int wave, int lane)
{
    #pragma unroll
    for (int i = 0; i < 2; ++i) {
        const __hip_bfloat16* gp = g + (size_t)(i * 512 + wave * 64 + lane) * 8;
        unsigned short* lp = l + (i * 512 + wave * 64) * 8;  // wave-uniform base
        glds16(gp, lp);
    }
}

// ---------------------------------------------------------------------------
// Shared 32xKx256 GEMM core (reg double-buffered).
__device__ __forceinline__ void mfma_gemm(
    const unsigned short* sA, int pitch,
    const __hip_bfloat16* Wswz, int KS, int lane, f32x4 acc[2][4])
{
    const int col = lane & 15, quad = lane >> 4;
    const unsigned short* a0p = sA + (size_t)col * pitch + quad * 8;
    const unsigned short* a1p = sA + (size_t)(16 + col) * pitch + quad * 8;
    const __hip_bfloat16* wp = Wswz + lane * 8;
    bf16x8 bc[4], bn[4], a0c, a1c, a0n, a1n;
    #pragma unroll
    for (int nt = 0; nt < 4; ++nt)
        bc[nt] = *reinterpret_cast<const bf16x8*>(wp + (size_t)nt * KS * 512);
    a0c = *reinterpret_cast<const bf16x8*>(a0p);
    a1c = *reinterpret_cast<const bf16x8*>(a1p);
    for (int ks = 0; ks < KS; ++ks) {
        if (ks + 1 < KS) {
            #pragma unroll
            for (int nt = 0; nt < 4; ++nt)
                bn[nt] = *reinterpret_cast<const bf16x8*>(
                    wp + ((size_t)nt * KS + ks + 1) * 512);
            a0n = *reinterpret_cast<const bf16x8*>(a0p + (ks + 1) * 32);
            a1n = *reinterpret_cast<const bf16x8*>(a1p + (ks + 1) * 32);
        }
        #pragma unroll
        for (int nt = 0; nt < 4; ++nt) {
            acc[0][nt] = __builtin_amdgcn_mfma_f32_16x16x32_bf16(a0c, bc[nt], acc[0][nt], 0, 0, 0);
            acc[1][nt] = __builtin_amdgcn_mfma_f32_16x16x32_bf16(a1c, bc[nt], acc[1][nt], 0, 0, 0);
        }
        #pragma unroll
        for (int nt = 0; nt < 4; ++nt) bc[nt] = bn[nt];
        a0c = a0n; a1c = a1n;
    }
}

// ---------------------------------------------------------------------------
__global__ void zero_kernel(float* __restrict__ p, int n) {
    int i = blockIdx.x * 256 + threadIdx.x;
    if (i < n) p[i] = 0.f;
}

// ---------------------------------------------------------------------------
// CSR build: histogram -> scan -> scatter (dst-sorted edge permutation).
__global__ void hist_kernel(const int* __restrict__ dst, int* __restrict__ hist, int n) {
    int i = blockIdx.x * 256 + threadIdx.x;
    if (i < n) atomicAdd(&hist[dst[i]], 1);
}

__global__ __launch_bounds__(256) void scan_kernel(
    const int* __restrict__ hist, int* __restrict__ cur,
    float* __restrict__ cntf, int n)
{
    __shared__ int part[256];
    const int tid = threadIdx.x;
    const int per = n >> 8;            // n is 4096 or 16384
    const int base = tid * per;
    int s = 0;
    for (int i = 0; i < per; ++i) s += hist[base + i];
    part[tid] = s;
    __syncthreads();
    #pragma unroll
    for (int off = 1; off < 256; off <<= 1) {
        int v = (tid >= off) ? part[tid - off] : 0;
        __syncthreads();
        part[tid] += v;
        __syncthreads();
    }
    int run = part[tid] - s;           // exclusive prefix of this chunk
    for (int i = 0; i < per; ++i) {
        const int h = hist[base + i];
        cur[base + i]  = run;
        cntf[base + i] = (float)h;
        run += h;
    }
}

__global__ void scatter_kernel(const int* __restrict__ dst, int* __restrict__ cur,
                               int* __restrict__ elist, int n) {
    int i = blockIdx.x * 256 + threadIdx.x;
    if (i < n) { int p = atomicAdd(&cur[dst[i]], 1); elist[p] = i; }
}

// ---------------------------------------------------------------------------
__global__ void wt_swz(const float* __restrict__ src,
                       __hip_bfloat16* __restrict__ dst, int K, int KS) {
    const int g  = blockIdx.x / KS;
    const int ks = blockIdx.x % KS;
    for (int i = threadIdx.x; i < 512; i += 256) {
        const int lane = i >> 3, j = i & 7;
        const int n = g * 16 + (lane & 15);
        const int k = ks * 32 + (lane >> 4) * 8 + j;
        const float v = (k < K) ? src[(size_t)k * 256 + n] : 0.f;
        dst[((size_t)(g * KS + ks) * 64 + lane) * 8 + j] = __float2bfloat16(v);
    }
}

// ---------------------------------------------------------------------------
// K fragment swizzle: blob[((key/16)*8+s)*512 + lane*8 + j]
//   = K[(key/16)*16 + (lane&15)][s*32 + (lane>>4)*8 + j].  Pure 16B permute.
__global__ __launch_bounds__(256) void kswz_kernel(
    const __hip_bfloat16* __restrict__ K, __hip_bfloat16* __restrict__ blob)
{
    const int c = blockIdx.x * 256 + threadIdx.x;   // chunk id, N*32 total
    const int lane = c & 63;
    const int s    = (c >> 6) & 7;
    const int kt   = c >> 9;
    const __hip_bfloat16* src =
        K + (size_t)(kt * 16 + (lane & 15)) * HD + s * 32 + (lane >> 4) * 8;
    *reinterpret_cast<uint4*>(blob + (size_t)c * 8) =
        *reinterpret_cast<const uint4*>(src);
}

// ---------------------------------------------------------------------------
// V fragment swizzle: blob[((key32)*16+dt)*512 + lane*8 + j]
//   = V[key32*32 + (lane>>4)*8 + j][dt*16 + (lane&15)].  One 32-key tile/block.
__global__ __launch_bounds__(256) void vswz_kernel(
    const __hip_bfloat16* __restrict__ V, __hip_bfloat16* __restrict__ blob)
{
    __shared__ unsigned short s[32][264];
    const int jt  = blockIdx.x;
    const int tid = threadIdx.x;
    {   // stage V rows [32][256] (b128)
        const int row = tid >> 3;
        const int d0  = (tid & 7) * 32;
        const __hip_bfloat16* vp = V + (size_t)(jt * 32 + row) * HD + d0;
        #pragma unroll
        for (int i = 0; i < 4; ++i)
            *reinterpret_cast<uint4*>(&s[row][d0 + 8 * i]) =
                *reinterpret_cast<const uint4*>(vp + 8 * i);
    }
    __syncthreads();
    {
        const int w    = tid >> 6;
        const int lane = tid & 63;
        const int col  = lane & 15;
        const int quad = lane >> 4;
        #pragma unroll
        for (int i = 0; i < 4; ++i) {
            const int dt = w + i * 4;
            unsigned short tmp[8];
            #pragma unroll
            for (int j = 0; j < 8; ++j)
                tmp[j] = s[quad * 8 + j][dt * 16 + col];
            *reinterpret_cast<uint4*>(
                blob + ((size_t)(jt * 16 + dt) * 64 + lane) * 8) =
                *reinterpret_cast<uint4*>(tmp);
        }
    }
}

// ---------------------------------------------------------------------------
// Edge MFMA kernel: 32 edges/block, edges taken in dst-sorted order (elist).
__global__ __launch_bounds__(256, 4) void edge_mfma(
    const float* __restrict__ coords, const float* __restrict__ h,
    const float* __restrict__ ef,
    const int* __restrict__ src, const int* __restrict__ dst,
    const int* __restrict__ elist,
    const __hip_bfloat16* __restrict__ W1s, const float* __restrict__ b1,
    const __hip_bfloat16* __restrict__ W2s, const float* __restrict__ b2,
    const __hip_bfloat16* __restrict__ Wc1s, const float* __restrict__ bc1,
    const float* __restrict__ wc2v, const float* __restrict__ bc2,
    float* __restrict__ aggr, float* __restrict__ xsum)
{
    __shared__ unsigned short sX[32][XP];     // also reused as fp32 [32][FP]
    __shared__ float sXrel[32][3];
    __shared__ int   sDst[32];
    __shared__ int   sSrc[32];
    __shared__ int   sE[32];
    __shared__ float sRedW[4][32];
    __shared__ float sPv[32];

    const int tid  = threadIdx.x;
    const int lane = tid & 63;
    const int wave = tid >> 6;
    const int col  = lane & 15;
    const int quad = lane >> 4;
    const int e0   = blockIdx.x * 32;

    // ---- edge meta: permuted id, endpoints, x_rel, RBF ----
    if (tid < 32) {
        const int e = elist[e0 + tid];
        const int s = src[e], d = dst[e];
        sE[tid] = e; sSrc[tid] = s; sDst[tid] = d;
        float d2 = 0.f;
        #pragma unroll
        for (int c = 0; c < 3; ++c) {
            const float xr = coords[s * 3 + c] - coords[d * 3 + c];
            sXrel[tid][c] = xr;
            d2 += xr * xr;
        }
        float sig = 1.0f;
        #pragma unroll
        for (int si = 0; si < NSIG; ++si) {
            sX[tid][528 + si] = f2bu(__expf(-d2 / sig));
            sig *= 1.5f;
        }
        sX[tid][543] = 0;
    }
    __syncthreads();

    // ---- gather h[src], h[dst] ----
    for (int i = tid; i < 32 * 128; i += 256) {
        const int row = i >> 7, c4 = i & 127;
        const int node = (c4 < 64) ? sSrc[row] : sDst[row];
        const float4 v = *reinterpret_cast<const float4*>(
            &h[(size_t)node * HD + (c4 & 63) * 4]);
        ushort4 u = { f2bu(v.x), f2bu(v.y), f2bu(v.z), f2bu(v.w) };
        *reinterpret_cast<ushort4*>(&sX[row][c4 * 4]) = u;
    }
    // ---- gather edge features (permuted rows) ----
    if (tid < 128) {
        const int row = tid >> 2, c = tid & 3;
        const float4 v = *reinterpret_cast<const float4*>(
            &ef[(size_t)sE[row] * EFD + c * 4]);
        ushort4 u = { f2bu(v.x), f2bu(v.y), f2bu(v.z), f2bu(v.w) };
        *reinterpret_cast<ushort4*>(&sX[row][512 + c * 4]) = u;
    }
    __syncthreads();

    f32x4 acc[2][4];
    f32x4 macc[2][4];   // message accumulators, survive the coords GEMM

    // ---- GEMM1: [32 x 544] @ W1 -> hidden, lrelu ----
    #pragma unroll
    for (int nt = 0; nt < 4; ++nt) {
        const float bv = b1[wave * 64 + nt * 16 + col];
        acc[0][nt] = { bv, bv, bv, bv };
        acc[1][nt] = { bv, bv, bv, bv };
    }
    mfma_gemm(&sX[0][0], XP, W1s + (size_t)(wave * 4) * 17 * 512, 17, lane, acc);
    __syncthreads();
    #pragma unroll
    for (int mt = 0; mt < 2; ++mt)
        #pragma unroll
        for (int nt = 0; nt < 4; ++nt)
            #pragma unroll
            for (int r = 0; r < 4; ++r)
                sX[mt * 16 + quad * 4 + r][wave * 64 + nt * 16 + col] =
                    f2bu(lrelu(acc[mt][nt][r]));
    __syncthreads();

    // ---- GEMM2: hidden @ W2 -> msg (kept fp32 in macc) ----
    #pragma unroll
    for (int nt = 0; nt < 4; ++nt) {
        const float bv = b2[wave * 64 + nt * 16 + col];
        macc[0][nt] = { bv, bv, bv, bv };
        macc[1][nt] = { bv, bv, bv, bv };
    }
    mfma_gemm(&sX[0][0], XP, W2s + (size_t)(wave * 4) * 8 * 512, 8, lane, macc);
    __syncthreads();
    #pragma unroll
    for (int mt = 0; mt < 2; ++mt)
        #pragma unroll
        for (int nt = 0; nt < 4; ++nt)
            #pragma unroll
            for (int r = 0; r < 4; ++r)
                sX[mt * 16 + quad * 4 + r][wave * 64 + nt * 16 + col] =
                    f2bu(macc[mt][nt][r]);
    __syncthreads();

    // ---- GEMM3: msg @ Wc1 -> lrelu -> dot wc2 (per-edge scalar p) ----
    #pragma unroll
    for (int nt = 0; nt < 4; ++nt) {
        const float bv = bc1[wave * 64 + nt * 16 + col];
        acc[0][nt] = { bv, bv, bv, bv };
        acc[1][nt] = { bv, bv, bv, bv };
    }
    mfma_gemm(&sX[0][0], XP, Wc1s + (size_t)(wave * 4) * 8 * 512, 8, lane, acc);
    float w2l[4];
    #pragma unroll
    for (int nt = 0; nt < 4; ++nt) w2l[nt] = wc2v[wave * 64 + nt * 16 + col];
    #pragma unroll
    for (int mt = 0; mt < 2; ++mt) {
        float pr[4] = { 0.f, 0.f, 0.f, 0.f };
        #pragma unroll
        for (int nt = 0; nt < 4; ++nt)
            #pragma unroll
            for (int r = 0; r < 4; ++r)
                pr[r] += lrelu(acc[mt][nt][r]) * w2l[nt];
        #pragma unroll
        for (int r = 0; r < 4; ++r) {
            #pragma unroll
            for (int off = 1; off < 16; off <<= 1) pr[r] += __shfl_xor(pr[r], off);
        }
        if (col == 0)
            #pragma unroll
            for (int r = 0; r < 4; ++r)
                sRedW[wave][mt * 16 + quad * 4 + r] = pr[r];
    }
    __syncthreads();

    // ---- dump fp32 messages into LDS (reuse sX), gather p per edge ----
    float* sF = reinterpret_cast<float*>(&sX[0][0]);   // [32][FP] floats
    #pragma unroll
    for (int mt = 0; mt < 2; ++mt)
        #pragma unroll
        for (int nt = 0; nt < 4; ++nt)
            #pragma unroll
            for (int r = 0; r < 4; ++r)
                sF[(mt * 16 + quad * 4 + r) * FP + wave * 64 + nt * 16 + col] =
                    macc[mt][nt][r];
    if (tid < 32)
        sPv[tid] = sRedW[0][tid] + sRedW[1][tid] + sRedW[2][tid] + sRedW[3][tid]
                 + bc2[0];
    __syncthreads();

    // ---- segmented flush: one atomic per (distinct dst x column) ----
    {
        const int c = tid;               // 256 threads = 256 columns
        float av = 0.f;
        int dprev = sDst[0];
        for (int row = 0; row < 32; ++row) {
            const int d = sDst[row];     // uniform across block -> no divergence
            if (d != dprev) {
                atomicAdd(&aggr[(size_t)dprev * HD + c], av);
                av = 0.f; dprev = d;
            }
            av += sF[row * FP + c];
        }
        atomicAdd(&aggr[(size_t)dprev * HD + c], av);
    }
    if (tid < 3) {
        const int c = tid;
        float av = 0.f;
        int dprev = sDst[0];
        for (int row = 0; row < 32; ++row) {
            const int d = sDst[row];
            if (d != dprev) {
                atomicAdd(&xsum[(size_t)dprev * 3 + c], av);
                av = 0.f; dprev = d;
            }
            av += sXrel[row][c] * sPv[row];
        }
        atomicAdd(&xsum[(size_t)dprev * 3 + c], av);
    }
}

// ---------------------------------------------------------------------------
// Node MFMA kernel: 32 nodes/block (unchanged).
__global__ __launch_bounds__(256, 4) void node_mfma(
    const float* __restrict__ aggr, const float* __restrict__ cnt,
    const __hip_bfloat16* __restrict__ cross, const float* __restrict__ orig,
    const float* __restrict__ hfeat,
    const __hip_bfloat16* __restrict__ WN1s, const float* __restrict__ b1,
    const __hip_bfloat16* __restrict__ WN2s, const float* __restrict__ b2,
    float* __restrict__ out)
{
    __shared__ unsigned short sXn[32][XPN];
    __shared__ float sInv[32];

    const int tid  = threadIdx.x;
    const int lane = tid & 63;
    const int wave = tid >> 6;
    const int col  = lane & 15;
    const int quad = lane >> 4;
    const int r0   = blockIdx.x * 32;

    if (tid < 32) sInv[tid] = 1.f / fmaxf(cnt[r0 + tid], 1.f);
    __syncthreads();

    for (int i = tid; i < 32 * 64; i += 256) {
        const int row = i >> 6, c4 = i & 63;
        const float inv = sInv[row];
        const float4 v = *reinterpret_cast<const float4*>(
            &aggr[(size_t)(r0 + row) * HD + c4 * 4]);
        ushort4 u = { f2bu(v.x * inv), f2bu(v.y * inv), f2bu(v.z * inv), f2bu(v.w * inv) };
        *reinterpret_cast<ushort4*>(&sXn[row][c4 * 4]) = u;
    }
    for (int i = tid; i < 32 * 64; i += 256) {
        const int row = i >> 6, c4 = i & 63;
        const ushort4 u = *reinterpret_cast<const ushort4*>(
            &cross[(size_t)(r0 + row) * HD + c4 * 4]);
        *reinterpret_cast<ushort4*>(&sXn[row][256 + c4 * 4]) = u;
    }
    for (int i = tid; i < 32 * 16; i += 256) {
        const int row = i >> 4, c4 = i & 15;
        const float4 v = *reinterpret_cast<const float4*>(
            &orig[(size_t)(r0 + row) * ORIGD + c4 * 4]);
        ushort4 u = { f2bu(v.x), f2bu(v.y), f2bu(v.z), f2bu(v.w) };
        *reinterpret_cast<ushort4*>(&sXn[row][512 + c4 * 4]) = u;
    }
    __syncthreads();

    f32x4 acc[2][4];

    #pragma unroll
    for (int nt = 0; nt < 4; ++nt) {
        const float bv = b1[wave * 64 + nt * 16 + col];
        acc[0][nt] = { bv, bv, bv, bv };
        acc[1][nt] = { bv, bv, bv, bv };
    }
    mfma_gemm(&sXn[0][0], XPN, WN1s + (size_t)(wave * 4) * 18 * 512, 18, lane, acc);
    __syncthreads();
    #pragma unroll
    for (int mt = 0; mt < 2; ++mt)
        #pragma unroll
        for (int nt = 0; nt < 4; ++nt)
            #pragma unroll
            for (int r = 0; r < 4; ++r)
                sXn[mt * 16 + quad * 4 + r][wave * 64 + nt * 16 + col] =
                    f2bu(lrelu(acc[mt][nt][r]));
    __syncthreads();

    #pragma unroll
    for (int nt = 0; nt < 4; ++nt) {
        const float bv = b2[wave * 64 + nt * 16 + col];
        acc[0][nt] = { bv, bv, bv, bv };
        acc[1][nt] = { bv, bv, bv, bv };
    }
    mfma_gemm(&sXn[0][0], XPN, WN2s + (size_t)(wave * 4) * 8 * 512, 8, lane, acc);
    #pragma unroll
    for (int mt = 0; mt < 2; ++mt)
        #pragma unroll
        for (int nt = 0; nt < 4; ++nt)
            #pragma unroll
            for (int r = 0; r < 4; ++r) {
                const int g = r0 + mt * 16 + quad * 4 + r;
                const int n = wave * 64 + nt * 16 + col;
                out[(size_t)g * HD + n] =
                    0.5f * acc[mt][nt][r] + 0.5f * hfeat[(size_t)g * HD + n];
            }
}

// ---------------------------------------------------------------------------
// Projection MFMA (unchanged).
__global__ __launch_bounds__(256, 4) void proj_mfma(
    const float* __restrict__ X, const __hip_bfloat16* __restrict__ Ws,
    __hip_bfloat16* __restrict__ out, int applyLrelu)
{
    __shared__ unsigned short sXp[32][XPP];
    const int tid  = threadIdx.x;
    const int lane = tid & 63;
    const int wave = tid >> 6;
    const int col  = lane & 15;
    const int quad = lane >> 4;
    const int r0   = blockIdx.x * 32;

    for (int i = tid; i < 32 * 64; i += 256) {
        const int row = i >> 6, c4 = i & 63;
        const float4 v = *reinterpret_cast<const float4*>(
            &X[(size_t)(r0 + row) * HD + c4 * 4]);
        ushort4 u = { f2bu(v.x), f2bu(v.y), f2bu(v.z), f2bu(v.w) };
        *reinterpret_cast<ushort4*>(&sXp[row][c4 * 4]) = u;
    }
    __syncthreads();

    f32x4 acc[2][4];
    #pragma unroll
    for (int nt = 0; nt < 4; ++nt) {
        acc[0][nt] = { 0.f, 0.f, 0.f, 0.f };
        acc[1][nt] = { 0.f, 0.f, 0.f, 0.f };
    }
    mfma_gemm(&sXp[0][0], XPP, Ws + (size_t)(wave * 4) * 8 * 512, 8, lane, acc);
    #pragma unroll
    for (int mt = 0; mt < 2; ++mt)
        #pragma unroll
        for (int nt = 0; nt < 4; ++nt)
            #pragma unroll
            for (int r = 0; r < 4; ++r) {
                float v = acc[mt][nt][r];
                if (applyLrelu) v = lrelu(v);
                out[(size_t)(r0 + mt * 16 + quad * 4 + r) * HD +
                    wave * 64 + nt * 16 + col] = __float2bfloat16(v);
            }
}

// ---------------------------------------------------------------------------
// Attention helpers.
__device__ __forceinline__ void load_mask(
    const float* __restrict__ maskG, int transposed, int R0, int j0,
    int wave, int quad, int col, float mv[2][4])
{
    if (!transposed) {
        #pragma unroll
        for (int t = 0; t < 2; ++t)
            #pragma unroll
            for (int r = 0; r < 4; ++r)
                mv[t][r] = maskG[(size_t)(R0 + wave * 16 + quad * 4 + r) * N_REC
                                 + j0 + col + 16 * t];
    } else {
        #pragma unroll
        for (int t = 0; t < 2; ++t)
            #pragma unroll
            for (int r = 0; r < 4; ++r)
                mv[t][r] = maskG[(size_t)(j0 + col + 16 * t) * N_REC
                                 + R0 + wave * 16 + quad * 4 + r];
    }
}

// One 32-key tile with defer-max online softmax (THR=8):
// skip wave-max reduce + rescale unless some lane's local max exceeds m+THR.
// l is kept as PER-LANE partials (2 cols each); reduced once at kernel end.
__device__ __forceinline__ void attn_tile(
    const unsigned short* sK, const unsigned short* sV,
    unsigned short (*sPw)[40], const bf16x8 qf[8], const float mv[2][4],
    int lane, int col, int quad, f32x4 o[16], float m[4], float l[4])
{
    // ---- S = Q K^T ----
    f32x4 sacc[2];
    sacc[0][0]=0.f; sacc[0][1]=0.f; sacc[0][2]=0.f; sacc[0][3]=0.f;
    sacc[1][0]=0.f; sacc[1][1]=0.f; sacc[1][2]=0.f; sacc[1][3]=0.f;
    #pragma unroll
    for (int t = 0; t < 2; ++t) {
        #pragma unroll
        for (int s = 0; s < 8; ++s) {
            bf16x8 kf = *reinterpret_cast<const bf16x8*>(
                &sK[(t * 8 + s) * 512 + lane * 8]);
            sacc[t] = __builtin_amdgcn_mfma_f32_16x16x32_bf16(qf[s], kf, sacc[t], 0, 0, 0);
        }
    }

    // ---- masked scores ----
    float a[2][4];
    #pragma unroll
    for (int t = 0; t < 2; ++t)
        #pragma unroll
        for (int r = 0; r < 4; ++r)
            a[t][r] = mv[t][r] * sacc[t][r] - 1000.f * (1.f - mv[t][r]);

    // ---- defer-max: rescale only when local max grows past m+8 ----
    float lm[4];
    #pragma unroll
    for (int r = 0; r < 4; ++r) lm[r] = fmaxf(a[0][r], a[1][r]);
    float w = lm[0] - m[0];
    #pragma unroll
    for (int r = 1; r < 4; ++r) w = fmaxf(w, lm[r] - m[r]);
    if (!__all(w <= 8.f)) {
        #pragma unroll
        for (int r = 0; r < 4; ++r) {
            float mx = lm[r];
            #pragma unroll
            for (int off = 1; off < 16; off <<= 1)
                mx = fmaxf(mx, __shfl_xor(mx, off));
            const float mn = fmaxf(m[r], mx);
            const float c  = __expf(m[r] - mn);
            m[r] = mn;
            l[r] *= c;
            #pragma unroll
            for (int dt = 0; dt < 16; ++dt) o[dt][r] *= c;
        }
    }

    // ---- P = exp(a - m), per-lane l partials ----
    #pragma unroll
    for (int r = 0; r < 4; ++r) {
        const float p0 = __expf(a[0][r] - m[r]);
        const float p1 = __expf(a[1][r] - m[r]);
        sPw[quad * 4 + r][col]      = f2bu(p0);
        sPw[quad * 4 + r][col + 16] = f2bu(p1);
        l[r] += p0 + p1;
    }

    // ---- O += P V ----
    bf16x8 pf = *reinterpret_cast<const bf16x8*>(&sPw[col][quad * 8]);
    #pragma unroll
    for (int dt = 0; dt < 16; ++dt) {
        bf16x8 vf = *reinterpret_cast<const bf16x8*>(&sV[dt * 512 + lane * 8]);
        o[dt] = __builtin_amdgcn_mfma_f32_16x16x32_bf16(pf, vf, o[dt], 0, 0, 0);
    }
}

// ---------------------------------------------------------------------------
// MFMA flash attention partial. 128 q-rows/block (8 waves x 16), 32-key
// tiles. K/V double-buffered in LDS via global_load_lds (zero-VGPR staging);
// masks prefetched one tile ahead into alternating reg sets. Per phase:
// vmcnt(0)+s_barrier (tile ready, prev buffer free), issue next tile's
// glds+mask loads, compute current tile.
__global__ __launch_bounds__(512) void attn_mfma(
    const __hip_bfloat16* __restrict__ Qb, const __hip_bfloat16* __restrict__ Kz,
    const __hip_bfloat16* __restrict__ Vz, const float* __restrict__ maskG,
    float* __restrict__ PO, float* __restrict__ PM, float* __restrict__ PL,
    int M, int chunkKeys, int transposed)
{
    __shared__ unsigned short sKb[2][8192];   // 2 x 16 KB
    __shared__ unsigned short sVb[2][8192];   // 2 x 16 KB
    __shared__ unsigned short sP[8][16][40];  // 10 KB

    const int tid  = threadIdx.x;
    const int lane = tid & 63;
    const int wave = tid >> 6;
    const int col  = lane & 15;
    const int quad = lane >> 4;
    const int R0   = blockIdx.x * 128;
    const int split = blockIdx.y;
    const int jbase = split * chunkKeys;

    bf16x8 qf[8];
    {
        const __hip_bfloat16* qp =
            Qb + (size_t)(R0 + wave * 16 + col) * HD + quad * 8;
        #pragma unroll
        for (int s = 0; s < 8; ++s)
            qf[s] = *reinterpret_cast<const bf16x8*>(qp + 32 * s);
    }

    f32x4 o[16];
    #pragma unroll
    for (int dt = 0; dt < 16; ++dt) { o[dt][0]=0.f; o[dt][1]=0.f; o[dt][2]=0.f; o[dt][3]=0.f; }
    float m[4], l[4];
    #pragma unroll
    for (int r = 0; r < 4; ++r) { m[r] = -INFINITY; l[r] = 0.f; }

    float mvA[2][4], mvB[2][4];

    // ---- prologue: tile 0 -> buf0 + mvA ----
    stage_tile(Kz + (size_t)jbase * 256, &sKb[0][0], wave, lane);
    stage_tile(Vz + (size_t)jbase * 256, &sVb[0][0], wave, lane);
    load_mask(maskG, transposed, R0, jbase, wave, quad, col, mvA);

    for (int jt = 0; jt < chunkKeys; jt += 64) {
        // ===== phase A: compute tile jt (buf0, mvA); stage jt+32 =====
        asm volatile("s_waitcnt vmcnt(0)" ::: "memory");
        __builtin_amdgcn_s_barrier();
        __builtin_amdgcn_sched_barrier(0);
        stage_tile(Kz + (size_t)(jbase + jt + 32) * 256, &sKb[1][0], wave, lane);
        stage_tile(Vz + (size_t)(jbase + jt + 32) * 256, &sVb[1][0], wave, lane);
        load_mask(maskG, transposed, R0, jbase + jt + 32, wave, quad, col, mvB);
        __builtin_amdgcn_sched_barrier(0);
        attn_tile(&sKb[0][0], &sVb[0][0], sP[wave], qf, mvA,
                  lane, col, quad, o, m, l);

        // ===== phase B: compute tile jt+32 (buf1, mvB); stage jt+64 =====
        asm volatile("s_waitcnt vmcnt(0)" ::: "memory");
        __builtin_amdgcn_s_barrier();
        __builtin_amdgcn_sched_barrier(0);
        if (jt + 64 < chunkKeys) {
            stage_tile(Kz + (size_t)(jbase + jt + 64) * 256, &sKb[0][0], wave, lane);
            stage_tile(Vz + (size_t)(jbase + jt + 64) * 256, &sVb[0][0], wave, lane);
            load_mask(maskG, transposed, R0, jbase + jt + 64, wave, quad, col, mvA);
        }
        __builtin_amdgcn_sched_barrier(0);
        attn_tile(&sKb[1][0], &sVb[1][0], sP[wave], qf, mvB,
                  lane, col, quad, o, m, l);
    }

    // ---- final l reduction (per-lane partials -> 16-lane row sums) ----
    #pragma unroll
    for (int r = 0; r < 4; ++r) {
        #pragma unroll
        for (int off = 1; off < 16; off <<= 1)
            l[r] += __shfl_xor(l[r], off);
    }

    #pragma unroll
    for (int dt = 0; dt < 16; ++dt)
        #pragma unroll
        for (int r = 0; r < 4; ++r) {
            const int row = R0 + wave * 16 + quad * 4 + r;
            PO[((size_t)split * M + row) * HD + dt * 16 + col] = o[dt][r];
        }
    if (col == 0) {
        #pragma unroll
        for (int r = 0; r < 4; ++r) {
            const int row = R0 + wave * 16 + quad * 4 + r;
            PM[(size_t)split * M + row] = m[r];
            PL[(size_t)split * M + row] = l[r];
        }
    }
}

// ---------------------------------------------------------------------------
__global__ void attn_combine(
    const float* __restrict__ PO, const float* __restrict__ PM,
    const float* __restrict__ PL, __hip_bfloat16* __restrict__ Out,
    int M, int nchunks)
{
    const int idx = blockIdx.x * 256 + threadIdx.x;
    const int row = idx >> 8;
    float mmax = -INFINITY;
    for (int c = 0; c < nchunks; ++c) mmax = fmaxf(mmax, PM[(size_t)c * M + row]);
    float denom = 0.f, acc = 0.f;
    for (int c = 0; c < nchunks; ++c) {
        const float w = __expf(PM[(size_t)c * M + row] - mmax);
        denom += PL[(size_t)c * M + row] * w;
        acc   += PO[(size_t)c * M * HD + idx] * w;
    }
    Out[idx] = __float2bfloat16(acc / denom);
}

// ---------------------------------------------------------------------------
__global__ void coords_fin(
    const float* __restrict__ coords, const float* __restrict__ origc,
    const float* __restrict__ xsum, const float* __restrict__ cnt,
    float* __restrict__ out, int n)
{
    const int i = blockIdx.x * 256 + threadIdx.x;
    if (i >= n * 3) return;
    const int node = i / 3;
    const float inv = 1.f / fmaxf(cnt[node], 1.f);
    out[i] = 0.25f * origc[i] + 0.75f * coords[i] + xsum[i] * inv;
}

// ---------------------------------------------------------------------------
extern "C" void kernel_launch(void* const* d_in, const int* in_sizes, int n_in,
                              void* d_out, int out_size, void* d_ws, size_t ws_size,
                              hipStream_t stream)
{
    const float* coords_lig = (const float*)d_in[0];
    const float* h_lig      = (const float*)d_in[1];
    const float* orig_lig   = (const float*)d_in[2];
    const float* origc_lig  = (const float*)d_in[3];
    const float* coords_rec = (const float*)d_in[4];
    const float* h_rec      = (const float*)d_in[5];
    const float* orig_rec   = (const float*)d_in[6];
    const float* origc_rec  = (const float*)d_in[7];
    const float* mask       = (const float*)d_in[8];
    const float* lig_ef     = (const float*)d_in[9];
    const float* rec_ef     = (const float*)d_in[10];
    const int* lig_src = (const int*)d_in[11];
    const int* lig_dst = (const int*)d_in[12];
    const int* rec_src = (const int*)d_in[13];
    const int* rec_dst = (const int*)d_in[14];
    const float* le_w1 = (const float*)d_in[15];
    const float* le_b1 = (const float*)d_in[16];
    const float* le_w2 = (const float*)d_in[17];
    const float* le_b2 = (const float*)d_in[18];
    const float* re_w1 = (const float*)d_in[19];
    const float* re_b1 = (const float*)d_in[20];
    const float* re_w2 = (const float*)d_in[21];
    const float* re_b2 = (const float*)d_in[22];
    const float* aql_w = (const float*)d_in[23];
    const float* akl_w = (const float*)d_in[24];
    const float* avl_w = (const float*)d_in[25];
    const float* aqr_w = (const float*)d_in[26];
    const float* akr_w = (const float*)d_in[27];
    const float* avr_w = (const float*)d_in[28];
    const float* nl_w1 = (const float*)d_in[29];
    const float* nl_b1 = (const float*)d_in[30];
    const float* nl_w2 = (const float*)d_in[31];
    const float* nl_b2 = (const float*)d_in[32];
    const float* nr_w1 = (const float*)d_in[33];
    const float* nr_b1 = (const float*)d_in[34];
    const float* nr_w2 = (const float*)d_in[35];
    const float* nr_b2 = (const float*)d_in[36];
    const float* cl_w1 = (const float*)d_in[37];
    const float* cl_b1 = (const float*)d_in[38];
    const float* cl_w2 = (const float*)d_in[39];
    const float* cl_b2 = (const float*)d_in[40];
    const float* cr_w1 = (const float*)d_in[41];
    const float* cr_b1 = (const float*)d_in[42];
    const float* cr_w2 = (const float*)d_in[43];
    const float* cr_b2 = (const float*)d_in[44];

    float* out = (float*)d_out;
    float* wsf = (float*)d_ws;

    // ---- fp32 accumulator + CSR zone ----
    const size_t AGGRL = 0;
    const size_t AGGRR = AGGRL + (size_t)N_LIG * HD;
    const size_t CNTL  = AGGRR + (size_t)N_REC * HD;
    const size_t CNTR  = CNTL + N_LIG;
    const size_t XSUML = CNTR + N_REC;
    const size_t XSUMR = XSUML + (size_t)N_LIG * 3;
    const size_t HISTL = XSUMR + (size_t)N_REC * 3;
    const size_t CURL  = HISTL + N_LIG;
    const size_t HISTR = CURL + N_LIG;
    const size_t CURR  = HISTR + N_REC;
    const size_t ZEND  = CURR + N_REC;          // zeroed through here
    const size_t ELISTL = ZEND;                 // not zeroed
    const size_t ELISTR = ELISTL + E_LIG_N;
    const size_t FEND   = ELISTR + E_REC_N;

    // ---- bf16 zone ----
    __hip_bfloat16* wsb = (__hip_bfloat16*)(wsf + FEND);
    const size_t QL  = 0;
    const size_t KL  = QL + (size_t)N_LIG * HD;
    const size_t VL  = KL + (size_t)N_LIG * HD;
    const size_t QR  = VL + (size_t)N_LIG * HD;
    const size_t KR  = QR + (size_t)N_REC * HD;
    const size_t VR  = KR + (size_t)N_REC * HD;
    const size_t CRL = VR + (size_t)N_REC * HD;
    const size_t CRR = CRL + (size_t)N_LIG * HD;
    const size_t KZL = CRR + (size_t)N_REC * HD;          // K swizzled lig
    const size_t VZL = KZL + (size_t)N_LIG * HD;          // V swizzled lig
    const size_t KZR = VZL + (size_t)N_LIG * HD;          // K swizzled rec
    const size_t VZR = KZR + (size_t)N_REC * HD;          // V swizzled rec
    const size_t EW1SZ = (size_t)16 * 17 * 512;
    const size_t KW256 = (size_t)16 * 8 * 512;
    const size_t NW1SZ = (size_t)16 * 18 * 512;
    const size_t SW_EL1 = VZR + (size_t)N_REC * HD;
    const size_t SW_EL2 = SW_EL1 + EW1SZ;
    const size_t SW_EC1 = SW_EL2 + KW256;
    const size_t SW_NL1 = SW_EC1 + KW256;
    const size_t SW_NL2 = SW_NL1 + NW1SZ;
    const size_t SW_ER1 = SW_NL2 + KW256;
    const size_t SW_ER2 = SW_ER1 + EW1SZ;
    const size_t SW_EC1R = SW_ER2 + KW256;
    const size_t SW_NR1 = SW_EC1R + KW256;
    const size_t SW_NR2 = SW_NR1 + NW1SZ;
    const size_t SW_PQL = SW_NR2 + KW256;
    const size_t SW_PKL = SW_PQL + KW256;
    const size_t SW_PVL = SW_PKL + KW256;
    const size_t SW_PQR = SW_PVL + KW256;
    const size_t SW_PKR = SW_PQR + KW256;
    const size_t SW_PVR = SW_PKR + KW256;
    const size_t BF_END = SW_PVR + KW256;

    // ---- split-K partial zone (fp32), dynamic splits ----
    float* wsp = (float*)(wsb + ((BF_END + 1) & ~(size_t)1));
    const size_t baseBytes = (size_t)((char*)wsp - (char*)d_ws);
    int SL = 16, SR = 4;
    {
        const size_t poElems16 = (size_t)16 * N_LIG * HD;
        const size_t need16 = baseBytes +
            (poElems16 + 2 * (size_t)16 * N_LIG) * sizeof(float);
        if (ws_size < need16) { SL = 8; SR = 2; }
    }
    const size_t PO_ = 0;
    const size_t PM_ = PO_ + (size_t)SL * N_LIG * HD;
    const size_t PL_ = PM_ + (size_t)SL * N_LIG;

    const size_t O_XL = 0;
    const size_t O_HL = O_XL + (size_t)N_LIG * 3;
    const size_t O_XR = O_HL + (size_t)N_LIG * HD;
    const size_t O_HR = O_XR + (size_t)N_REC * 3;

    // 1) zero atomic accumulators + CSR hist/cursors
    zero_kernel<<<((int)ZEND + 255) / 256, 256, 0, stream>>>(wsf, (int)ZEND);

    // 1b) CSR build: dst-sorted edge permutations (also produces fp32 counts)
    hist_kernel<<<E_LIG_N / 256, 256, 0, stream>>>(lig_dst, (int*)(wsf + HISTL), E_LIG_N);
    hist_kernel<<<E_REC_N / 256, 256, 0, stream>>>(rec_dst, (int*)(wsf + HISTR), E_REC_N);
    scan_kernel<<<1, 256, 0, stream>>>((int*)(wsf + HISTL), (int*)(wsf + CURL),
                                       wsf + CNTL, N_LIG);
    scan_kernel<<<1, 256, 0, stream>>>((int*)(wsf + HISTR), (int*)(wsf + CURR),
                                       wsf + CNTR, N_REC);
    scatter_kernel<<<E_LIG_N / 256, 256, 0, stream>>>(
        lig_dst, (int*)(wsf + CURL), (int*)(wsf + ELISTL), E_LIG_N);
    scatter_kernel<<<E_REC_N / 256, 256, 0, stream>>>(
        rec_dst, (int*)(wsf + CURR), (int*)(wsf + ELISTR), E_REC_N);

    // 2) weight swizzles
    wt_swz<<<16 * 17, 256, 0, stream>>>(le_w1, wsb + SW_EL1, EIN, 17);
    wt_swz<<<16 * 8,  256, 0, stream>>>(le_w2, wsb + SW_EL2, 256, 8);
    wt_swz<<<16 * 8,  256, 0, stream>>>(cl_w1, wsb + SW_EC1, 256, 8);
    wt_swz<<<16 * 18, 256, 0, stream>>>(nl_w1, wsb + SW_NL1, 576, 18);
    wt_swz<<<16 * 8,  256, 0, stream>>>(nl_w2, wsb + SW_NL2, 256, 8);
    wt_swz<<<16 * 17, 256, 0, stream>>>(re_w1, wsb + SW_ER1, EIN, 17);
    wt_swz<<<16 * 8,  256, 0, stream>>>(re_w2, wsb + SW_ER2, 256, 8);
    wt_swz<<<16 * 8,  256, 0, stream>>>(cr_w1, wsb + SW_EC1R, 256, 8);
    wt_swz<<<16 * 18, 256, 0, stream>>>(nr_w1, wsb + SW_NR1, 576, 18);
    wt_swz<<<16 * 8,  256, 0, stream>>>(nr_w2, wsb + SW_NR2, 256, 8);
    wt_swz<<<16 * 8,  256, 0, stream>>>(aql_w, wsb + SW_PQL, 256, 8);
    wt_swz<<<16 * 8,  256, 0, stream>>>(akl_w, wsb + SW_PKL, 256, 8);
    wt_swz<<<16 * 8,  256, 0, stream>>>(avl_w, wsb + SW_PVL, 256, 8);
    wt_swz<<<16 * 8,  256, 0, stream>>>(aqr_w, wsb + SW_PQR, 256, 8);
    wt_swz<<<16 * 8,  256, 0, stream>>>(akr_w, wsb + SW_PKR, 256, 8);
    wt_swz<<<16 * 8,  256, 0, stream>>>(avr_w, wsb + SW_PVR, 256, 8);

    // 3) edge MFMA kernels (dst-sorted order, segmented atomics)
    edge_mfma<<<E_LIG_N / 32, 256, 0, stream>>>(
        coords_lig, h_lig, lig_ef, lig_src, lig_dst, (const int*)(wsf + ELISTL),
        wsb + SW_EL1, le_b1, wsb + SW_EL2, le_b2, wsb + SW_EC1, cl_b1, cl_w2, cl_b2,
        wsf + AGGRL, wsf + XSUML);
    edge_mfma<<<E_REC_N / 32, 256, 0, stream>>>(
        coords_rec, h_rec, rec_ef, rec_src, rec_dst, (const int*)(wsf + ELISTR),
        wsb + SW_ER1, re_b1, wsb + SW_ER2, re_b2, wsb + SW_EC1R, cr_b1, cr_w2, cr_b2,
        wsf + AGGRR, wsf + XSUMR);

    // 4) projections -> bf16 (MFMA), then K/V fragment swizzles
    proj_mfma<<<N_LIG / 32, 256, 0, stream>>>(h_lig, wsb + SW_PQL, wsb + QL, 1);
    proj_mfma<<<N_LIG / 32, 256, 0, stream>>>(h_lig, wsb + SW_PKL, wsb + KL, 1);
    proj_mfma<<<N_LIG / 32, 256, 0, stream>>>(h_lig, wsb + SW_PVL, wsb + VL, 0);
    proj_mfma<<<N_REC / 32, 256, 0, stream>>>(h_rec, wsb + SW_PQR, wsb + QR, 1);
    proj_mfma<<<N_REC / 32, 256, 0, stream>>>(h_rec, wsb + SW_PKR, wsb + KR, 1);
    proj_mfma<<<N_REC / 32, 256, 0, stream>>>(h_rec, wsb + SW_PVR, wsb + VR, 0);
    kswz_kernel<<<N_LIG / 8, 256, 0, stream>>>(wsb + KL, wsb + KZL);
    kswz_kernel<<<N_REC / 8, 256, 0, stream>>>(wsb + KR, wsb + KZR);
    vswz_kernel<<<N_LIG / 32, 256, 0, stream>>>(wsb + VL, wsb + VZL);
    vswz_kernel<<<N_REC / 32, 256, 0, stream>>>(wsb + VR, wsb + VZR);

    // 5) MFMA flash attention, split-K + combine
    {
        dim3 gl(N_LIG / 128, SL);
        attn_mfma<<<gl, 512, 0, stream>>>(wsb + QL, wsb + KZR, wsb + VZR, mask,
                                          wsp + PO_, wsp + PM_, wsp + PL_,
                                          N_LIG, N_REC / SL, 0);
        attn_combine<<<N_LIG, 256, 0, stream>>>(
            wsp + PO_, wsp + PM_, wsp + PL_, wsb + CRL, N_LIG, SL);

        dim3 gr(N_REC / 128, SR);
        attn_mfma<<<gr, 512, 0, stream>>>(wsb + QR, wsb + KZL, wsb + VZL, mask,
                                          wsp + PO_, wsp + PM_, wsp + PL_,
                                          N_REC, N_LIG / SR, 1);
        attn_combine<<<N_REC, 256, 0, stream>>>(
            wsp + PO_, wsp + PM_, wsp + PL_, wsb + CRR, N_REC, SR);
    }

    // 6) coordinate outputs
    coords_fin<<<(N_LIG * 3 + 255) / 256, 256, 0, stream>>>(
        coords_lig, origc_lig, wsf + XSUML, wsf + CNTL, out + O_XL, N_LIG);
    coords_fin<<<(N_REC * 3 + 255) / 256, 256, 0, stream>>>(
        coords_rec, origc_rec, wsf + XSUMR, wsf + CNTR, out + O_XR, N_REC);

    // 7) node MFMA kernels
    node_mfma<<<N_LIG / 32, 256, 0, stream>>>(
        wsf + AGGRL, wsf + CNTL, wsb + CRL, orig_lig, h_lig,
        wsb + SW_NL1, nl_b1, wsb + SW_NL2, nl_b2, out + O_HL);
    node_mfma<<<N_REC / 32, 256, 0, stream>>>(
        wsf + AGGRR, wsf + CNTR, wsb + CRR, orig_rec, h_rec,
        wsb + SW_NR1, nr_b1, wsb + SW_NR2, nr_b2, out + O_HR);

    (void)in_sizes; (void)n_in; (void)out_size;
}

// Round 7
// 1299.890 us; speedup vs baseline: 1.6351x; 1.0109x over previous
//
#include <hip/hip_runtime.h>
#include <hip/hip_bf16.h>

// ---------------------------------------------------------------------------
// IEGMN layer, MI355X round-15: pre-converted bf16 operand blobs.
// h and edge_feat are converted fp32->bf16 ONCE (f2b_kernel); edge_mfma and
// proj_mfma staging become pure uint4 copies (no per-gather converts).
//   zero_kernel  : zero atomic accumulators + CSR hist/cursors
//   f2b_kernel   : fp32 -> bf16 blob (vectorized, 8 elems/thread)
//   hist/scan/scatter : CSR build (dst-sorted edge permutation)
//   wt_swz       : pack weights fp32[K][256] -> bf16 fragment-ordered blobs
//   edge_mfma    : gather(bf16) + RBF + edge MLP + coords MLP, dst-sorted;
//                  per-block segment reduction -> few atomics/block
//   proj_mfma    : q/k/v projections from bf16 h -> bf16 ws (MFMA)
//   kswz_kernel  : K [N][256] -> fragment-ordered blob
//   vswz_kernel  : V [N][256] -> fragment-ordered blob (LDS transpose)
//   attn_mfma    : flash attention partial (split-K), 8 waves x 16 q-rows,
//                  glds LDS double-buffer + defer-max softmax (r14, proven)
//   attn_combine : merge splits -> bf16 cross features
//   coords_fin   : x_ev -> out (fp32)
//   node_mfma    : node MLP + skip -> out (fp32, MFMA)
// ---------------------------------------------------------------------------

#define N_LIG   4096
#define N_REC   16384
#define E_LIG_N 65536
#define E_REC_N 262144
#define HD      256
#define ORIGD   64
#define EFD     16
#define NSIG    15
#define EIN     543      // 2*HD + EFD + NSIG
#define XP      552      // edge sX pitch (bf16 elems), 544 used
#define XPN     584      // node sX pitch, 576 used
#define XPP     264      // proj sX pitch, 256 used
#define FP      264      // fp32 reuse pitch inside sX (floats)

typedef __bf16 bf16x8 __attribute__((ext_vector_type(8)));
typedef float  f32x4  __attribute__((ext_vector_type(4)));

__device__ __forceinline__ float lrelu(float x) { return x > 0.f ? x : 0.01f * x; }
__device__ __forceinline__ unsigned short f2bu(float f) {
    __hip_bfloat16 h = __float2bfloat16(f);
    return *reinterpret_cast<unsigned short*>(&h);
}

// Direct global->LDS async copy, 16B per lane.
__device__ __forceinline__ void glds16(const void* g, void* l) {
    __builtin_amdgcn_global_load_lds(
        (const __attribute__((address_space(1))) void*)g,
        (__attribute__((address_space(3))) void*)l,
        16, 0, 0);
}

// Stage 16KB (one 32-key K or V tile) into LDS with 512 threads: 2 glds/thr.
__device__ __forceinline__ void stage_tile(
    const __hip_bfloat16* g, unsigned short* l, int wave, int lane)
{
    #pragma unroll
    for (int i = 0; i < 2; ++i) {
        const __hip_bfloat16* gp = g + (size_t)(i * 512 + wave * 64 + lane) * 8;
        unsigned short* lp = l + (i * 512 + wave * 64) * 8;  // wave-uniform base
        glds16(gp, lp);
    }
}

// ---------------------------------------------------------------------------
// Shared 32xKx256 GEMM core (reg double-buffered).
__device__ __forceinline__ void mfma_gemm(
    const unsigned short* sA, int pitch,
    const __hip_bfloat16* Wswz, int KS, int lane, f32x4 acc[2][4])
{
    const int col = lane & 15, quad = lane >> 4;
    const unsigned short* a0p = sA + (size_t)col * pitch + quad * 8;
    const unsigned short* a1p = sA + (size_t)(16 + col) * pitch + quad * 8;
    const __hip_bfloat16* wp = Wswz + lane * 8;
    bf16x8 bc[4], bn[4], a0c, a1c, a0n, a1n;
    #pragma unroll
    for (int nt = 0; nt < 4; ++nt)
        bc[nt] = *reinterpret_cast<const bf16x8*>(wp + (size_t)nt * KS * 512);
    a0c = *reinterpret_cast<const bf16x8*>(a0p);
    a1c = *reinterpret_cast<const bf16x8*>(a1p);
    for (int ks = 0; ks < KS; ++ks) {
        if (ks + 1 < KS) {
            #pragma unroll
            for (int nt = 0; nt < 4; ++nt)
                bn[nt] = *reinterpret_cast<const bf16x8*>(
                    wp + ((size_t)nt * KS + ks + 1) * 512);
            a0n = *reinterpret_cast<const bf16x8*>(a0p + (ks + 1) * 32);
            a1n = *reinterpret_cast<const bf16x8*>(a1p + (ks + 1) * 32);
        }
        #pragma unroll
        for (int nt = 0; nt < 4; ++nt) {
            acc[0][nt] = __builtin_amdgcn_mfma_f32_16x16x32_bf16(a0c, bc[nt], acc[0][nt], 0, 0, 0);
            acc[1][nt] = __builtin_amdgcn_mfma_f32_16x16x32_bf16(a1c, bc[nt], acc[1][nt], 0, 0, 0);
        }
        #pragma unroll
        for (int nt = 0; nt < 4; ++nt) bc[nt] = bn[nt];
        a0c = a0n; a1c = a1n;
    }
}

// ---------------------------------------------------------------------------
__global__ void zero_kernel(float* __restrict__ p, int n) {
    int i = blockIdx.x * 256 + threadIdx.x;
    if (i < n) p[i] = 0.f;
}

// ---------------------------------------------------------------------------
// fp32 -> bf16 blob, 8 elems/thread (vectorized).
__global__ void f2b_kernel(const float* __restrict__ src,
                           __hip_bfloat16* __restrict__ dst, int n8) {
    const int i = blockIdx.x * 256 + threadIdx.x;
    if (i >= n8) return;
    const float4 a = *reinterpret_cast<const float4*>(src + (size_t)i * 8);
    const float4 b = *reinterpret_cast<const float4*>(src + (size_t)i * 8 + 4);
    ushort4 u0 = { f2bu(a.x), f2bu(a.y), f2bu(a.z), f2bu(a.w) };
    ushort4 u1 = { f2bu(b.x), f2bu(b.y), f2bu(b.z), f2bu(b.w) };
    unsigned short* d = (unsigned short*)dst + (size_t)i * 8;
    *reinterpret_cast<ushort4*>(d)     = u0;
    *reinterpret_cast<ushort4*>(d + 4) = u1;
}

// ---------------------------------------------------------------------------
// CSR build: histogram -> scan -> scatter (dst-sorted edge permutation).
__global__ void hist_kernel(const int* __restrict__ dst, int* __restrict__ hist, int n) {
    int i = blockIdx.x * 256 + threadIdx.x;
    if (i < n) atomicAdd(&hist[dst[i]], 1);
}

__global__ __launch_bounds__(256) void scan_kernel(
    const int* __restrict__ hist, int* __restrict__ cur,
    float* __restrict__ cntf, int n)
{
    __shared__ int part[256];
    const int tid = threadIdx.x;
    const int per = n >> 8;            // n is 4096 or 16384
    const int base = tid * per;
    int s = 0;
    for (int i = 0; i < per; ++i) s += hist[base + i];
    part[tid] = s;
    __syncthreads();
    #pragma unroll
    for (int off = 1; off < 256; off <<= 1) {
        int v = (tid >= off) ? part[tid - off] : 0;
        __syncthreads();
        part[tid] += v;
        __syncthreads();
    }
    int run = part[tid] - s;           // exclusive prefix of this chunk
    for (int i = 0; i < per; ++i) {
        const int h = hist[base + i];
        cur[base + i]  = run;
        cntf[base + i] = (float)h;
        run += h;
    }
}

__global__ void scatter_kernel(const int* __restrict__ dst, int* __restrict__ cur,
                               int* __restrict__ elist, int n) {
    int i = blockIdx.x * 256 + threadIdx.x;
    if (i < n) { int p = atomicAdd(&cur[dst[i]], 1); elist[p] = i; }
}

// ---------------------------------------------------------------------------
__global__ void wt_swz(const float* __restrict__ src,
                       __hip_bfloat16* __restrict__ dst, int K, int KS) {
    const int g  = blockIdx.x / KS;
    const int ks = blockIdx.x % KS;
    for (int i = threadIdx.x; i < 512; i += 256) {
        const int lane = i >> 3, j = i & 7;
        const int n = g * 16 + (lane & 15);
        const int k = ks * 32 + (lane >> 4) * 8 + j;
        const float v = (k < K) ? src[(size_t)k * 256 + n] : 0.f;
        dst[((size_t)(g * KS + ks) * 64 + lane) * 8 + j] = __float2bfloat16(v);
    }
}

// ---------------------------------------------------------------------------
// K fragment swizzle: pure 16B permute.
__global__ __launch_bounds__(256) void kswz_kernel(
    const __hip_bfloat16* __restrict__ K, __hip_bfloat16* __restrict__ blob)
{
    const int c = blockIdx.x * 256 + threadIdx.x;   // chunk id, N*32 total
    const int lane = c & 63;
    const int s    = (c >> 6) & 7;
    const int kt   = c >> 9;
    const __hip_bfloat16* src =
        K + (size_t)(kt * 16 + (lane & 15)) * HD + s * 32 + (lane >> 4) * 8;
    *reinterpret_cast<uint4*>(blob + (size_t)c * 8) =
        *reinterpret_cast<const uint4*>(src);
}

// ---------------------------------------------------------------------------
// V fragment swizzle: LDS-tiled transpose, one 32-key tile/block.
__global__ __launch_bounds__(256) void vswz_kernel(
    const __hip_bfloat16* __restrict__ V, __hip_bfloat16* __restrict__ blob)
{
    __shared__ unsigned short s[32][264];
    const int jt  = blockIdx.x;
    const int tid = threadIdx.x;
    {   // stage V rows [32][256] (b128)
        const int row = tid >> 3;
        const int d0  = (tid & 7) * 32;
        const __hip_bfloat16* vp = V + (size_t)(jt * 32 + row) * HD + d0;
        #pragma unroll
        for (int i = 0; i < 4; ++i)
            *reinterpret_cast<uint4*>(&s[row][d0 + 8 * i]) =
                *reinterpret_cast<const uint4*>(vp + 8 * i);
    }
    __syncthreads();
    {
        const int w    = tid >> 6;
        const int lane = tid & 63;
        const int col  = lane & 15;
        const int quad = lane >> 4;
        #pragma unroll
        for (int i = 0; i < 4; ++i) {
            const int dt = w + i * 4;
            unsigned short tmp[8];
            #pragma unroll
            for (int j = 0; j < 8; ++j)
                tmp[j] = s[quad * 8 + j][dt * 16 + col];
            *reinterpret_cast<uint4*>(
                blob + ((size_t)(jt * 16 + dt) * 64 + lane) * 8) =
                *reinterpret_cast<uint4*>(tmp);
        }
    }
}

// ---------------------------------------------------------------------------
// Edge MFMA kernel: 32 edges/block, edges taken in dst-sorted order (elist).
// h and ef come from pre-converted bf16 blobs: staging = pure uint4 copies.
__global__ __launch_bounds__(256, 4) void edge_mfma(
    const float* __restrict__ coords, const __hip_bfloat16* __restrict__ hb,
    const __hip_bfloat16* __restrict__ efb,
    const int* __restrict__ src, const int* __restrict__ dst,
    const int* __restrict__ elist,
    const __hip_bfloat16* __restrict__ W1s, const float* __restrict__ b1,
    const __hip_bfloat16* __restrict__ W2s, const float* __restrict__ b2,
    const __hip_bfloat16* __restrict__ Wc1s, const float* __restrict__ bc1,
    const float* __restrict__ wc2v, const float* __restrict__ bc2,
    float* __restrict__ aggr, float* __restrict__ xsum)
{
    __shared__ unsigned short sX[32][XP];     // also reused as fp32 [32][FP]
    __shared__ float sXrel[32][3];
    __shared__ int   sDst[32];
    __shared__ int   sSrc[32];
    __shared__ int   sE[32];
    __shared__ float sRedW[4][32];
    __shared__ float sPv[32];

    const int tid  = threadIdx.x;
    const int lane = tid & 63;
    const int wave = tid >> 6;
    const int col  = lane & 15;
    const int quad = lane >> 4;
    const int e0   = blockIdx.x * 32;

    // ---- edge meta: permuted id, endpoints, x_rel, RBF ----
    if (tid < 32) {
        const int e = elist[e0 + tid];
        const int s = src[e], d = dst[e];
        sE[tid] = e; sSrc[tid] = s; sDst[tid] = d;
        float d2 = 0.f;
        #pragma unroll
        for (int c = 0; c < 3; ++c) {
            const float xr = coords[s * 3 + c] - coords[d * 3 + c];
            sXrel[tid][c] = xr;
            d2 += xr * xr;
        }
        float sig = 1.0f;
        #pragma unroll
        for (int si = 0; si < NSIG; ++si) {
            sX[tid][528 + si] = f2bu(__expf(-d2 / sig));
            sig *= 1.5f;
        }
        sX[tid][543] = 0;
    }
    __syncthreads();

    // ---- gather h[src], h[dst] (bf16, uint4 copies) ----
    for (int i = tid; i < 32 * 64; i += 256) {
        const int row = i >> 6, c = i & 63;
        const int node = (c < 32) ? sSrc[row] : sDst[row];
        const int chunk = c & 31;
        *reinterpret_cast<uint4*>(&sX[row][(c < 32 ? 0 : 256) + chunk * 8]) =
            *reinterpret_cast<const uint4*>(&hb[(size_t)node * HD + chunk * 8]);
    }
    // ---- gather edge features (bf16, permuted rows) ----
    if (tid < 64) {
        const int row = tid >> 1, hh = tid & 1;
        *reinterpret_cast<uint4*>(&sX[row][512 + hh * 8]) =
            *reinterpret_cast<const uint4*>(&efb[(size_t)sE[row] * EFD + hh * 8]);
    }
    __syncthreads();

    f32x4 acc[2][4];
    f32x4 macc[2][4];   // message accumulators, survive the coords GEMM

    // ---- GEMM1: [32 x 544] @ W1 -> hidden, lrelu ----
    #pragma unroll
    for (int nt = 0; nt < 4; ++nt) {
        const float bv = b1[wave * 64 + nt * 16 + col];
        acc[0][nt] = { bv, bv, bv, bv };
        acc[1][nt] = { bv, bv, bv, bv };
    }
    mfma_gemm(&sX[0][0], XP, W1s + (size_t)(wave * 4) * 17 * 512, 17, lane, acc);
    __syncthreads();
    #pragma unroll
    for (int mt = 0; mt < 2; ++mt)
        #pragma unroll
        for (int nt = 0; nt < 4; ++nt)
            #pragma unroll
            for (int r = 0; r < 4; ++r)
                sX[mt * 16 + quad * 4 + r][wave * 64 + nt * 16 + col] =
                    f2bu(lrelu(acc[mt][nt][r]));
    __syncthreads();

    // ---- GEMM2: hidden @ W2 -> msg (kept fp32 in macc) ----
    #pragma unroll
    for (int nt = 0; nt < 4; ++nt) {
        const float bv = b2[wave * 64 + nt * 16 + col];
        macc[0][nt] = { bv, bv, bv, bv };
        macc[1][nt] = { bv, bv, bv, bv };
    }
    mfma_gemm(&sX[0][0], XP, W2s + (size_t)(wave * 4) * 8 * 512, 8, lane, macc);
    __syncthreads();
    #pragma unroll
    for (int mt = 0; mt < 2; ++mt)
        #pragma unroll
        for (int nt = 0; nt < 4; ++nt)
            #pragma unroll
            for (int r = 0; r < 4; ++r)
                sX[mt * 16 + quad * 4 + r][wave * 64 + nt * 16 + col] =
                    f2bu(macc[mt][nt][r]);
    __syncthreads();

    // ---- GEMM3: msg @ Wc1 -> lrelu -> dot wc2 (per-edge scalar p) ----
    #pragma unroll
    for (int nt = 0; nt < 4; ++nt) {
        const float bv = bc1[wave * 64 + nt * 16 + col];
        acc[0][nt] = { bv, bv, bv, bv };
        acc[1][nt] = { bv, bv, bv, bv };
    }
    mfma_gemm(&sX[0][0], XP, Wc1s + (size_t)(wave * 4) * 8 * 512, 8, lane, acc);
    float w2l[4];
    #pragma unroll
    for (int nt = 0; nt < 4; ++nt) w2l[nt] = wc2v[wave * 64 + nt * 16 + col];
    #pragma unroll
    for (int mt = 0; mt < 2; ++mt) {
        float pr[4] = { 0.f, 0.f, 0.f, 0.f };
        #pragma unroll
        for (int nt = 0; nt < 4; ++nt)
            #pragma unroll
            for (int r = 0; r < 4; ++r)
                pr[r] += lrelu(acc[mt][nt][r]) * w2l[nt];
        #pragma unroll
        for (int r = 0; r < 4; ++r) {
            #pragma unroll
            for (int off = 1; off < 16; off <<= 1) pr[r] += __shfl_xor(pr[r], off);
        }
        if (col == 0)
            #pragma unroll
            for (int r = 0; r < 4; ++r)
                sRedW[wave][mt * 16 + quad * 4 + r] = pr[r];
    }
    __syncthreads();

    // ---- dump fp32 messages into LDS (reuse sX), gather p per edge ----
    float* sF = reinterpret_cast<float*>(&sX[0][0]);   // [32][FP] floats
    #pragma unroll
    for (int mt = 0; mt < 2; ++mt)
        #pragma unroll
        for (int nt = 0; nt < 4; ++nt)
            #pragma unroll
            for (int r = 0; r < 4; ++r)
                sF[(mt * 16 + quad * 4 + r) * FP + wave * 64 + nt * 16 + col] =
                    macc[mt][nt][r];
    if (tid < 32)
        sPv[tid] = sRedW[0][tid] + sRedW[1][tid] + sRedW[2][tid] + sRedW[3][tid]
                 + bc2[0];
    __syncthreads();

    // ---- segmented flush: one atomic per (distinct dst x column) ----
    {
        const int c = tid;               // 256 threads = 256 columns
        float av = 0.f;
        int dprev = sDst[0];
        for (int row = 0; row < 32; ++row) {
            const int d = sDst[row];     // uniform across block -> no divergence
            if (d != dprev) {
                atomicAdd(&aggr[(size_t)dprev * HD + c], av);
                av = 0.f; dprev = d;
            }
            av += sF[row * FP + c];
        }
        atomicAdd(&aggr[(size_t)dprev * HD + c], av);
    }
    if (tid < 3) {
        const int c = tid;
        float av = 0.f;
        int dprev = sDst[0];
        for (int row = 0; row < 32; ++row) {
            const int d = sDst[row];
            if (d != dprev) {
                atomicAdd(&xsum[(size_t)dprev * 3 + c], av);
                av = 0.f; dprev = d;
            }
            av += sXrel[row][c] * sPv[row];
        }
        atomicAdd(&xsum[(size_t)dprev * 3 + c], av);
    }
}

// ---------------------------------------------------------------------------
// Node MFMA kernel: 32 nodes/block (unchanged).
__global__ __launch_bounds__(256, 4) void node_mfma(
    const float* __restrict__ aggr, const float* __restrict__ cnt,
    const __hip_bfloat16* __restrict__ cross, const float* __restrict__ orig,
    const float* __restrict__ hfeat,
    const __hip_bfloat16* __restrict__ WN1s, const float* __restrict__ b1,
    const __hip_bfloat16* __restrict__ WN2s, const float* __restrict__ b2,
    float* __restrict__ out)
{
    __shared__ unsigned short sXn[32][XPN];
    __shared__ float sInv[32];

    const int tid  = threadIdx.x;
    const int lane = tid & 63;
    const int wave = tid >> 6;
    const int col  = lane & 15;
    const int quad = lane >> 4;
    const int r0   = blockIdx.x * 32;

    if (tid < 32) sInv[tid] = 1.f / fmaxf(cnt[r0 + tid], 1.f);
    __syncthreads();

    for (int i = tid; i < 32 * 64; i += 256) {
        const int row = i >> 6, c4 = i & 63;
        const float inv = sInv[row];
        const float4 v = *reinterpret_cast<const float4*>(
            &aggr[(size_t)(r0 + row) * HD + c4 * 4]);
        ushort4 u = { f2bu(v.x * inv), f2bu(v.y * inv), f2bu(v.z * inv), f2bu(v.w * inv) };
        *reinterpret_cast<ushort4*>(&sXn[row][c4 * 4]) = u;
    }
    for (int i = tid; i < 32 * 64; i += 256) {
        const int row = i >> 6, c4 = i & 63;
        const ushort4 u = *reinterpret_cast<const ushort4*>(
            &cross[(size_t)(r0 + row) * HD + c4 * 4]);
        *reinterpret_cast<ushort4*>(&sXn[row][256 + c4 * 4]) = u;
    }
    for (int i = tid; i < 32 * 16; i += 256) {
        const int row = i >> 4, c4 = i & 15;
        const float4 v = *reinterpret_cast<const float4*>(
            &orig[(size_t)(r0 + row) * ORIGD + c4 * 4]);
        ushort4 u = { f2bu(v.x), f2bu(v.y), f2bu(v.z), f2bu(v.w) };
        *reinterpret_cast<ushort4*>(&sXn[row][512 + c4 * 4]) = u;
    }
    __syncthreads();

    f32x4 acc[2][4];

    #pragma unroll
    for (int nt = 0; nt < 4; ++nt) {
        const float bv = b1[wave * 64 + nt * 16 + col];
        acc[0][nt] = { bv, bv, bv, bv };
        acc[1][nt] = { bv, bv, bv, bv };
    }
    mfma_gemm(&sXn[0][0], XPN, WN1s + (size_t)(wave * 4) * 18 * 512, 18, lane, acc);
    __syncthreads();
    #pragma unroll
    for (int mt = 0; mt < 2; ++mt)
        #pragma unroll
        for (int nt = 0; nt < 4; ++nt)
            #pragma unroll
            for (int r = 0; r < 4; ++r)
                sXn[mt * 16 + quad * 4 + r][wave * 64 + nt * 16 + col] =
                    f2bu(lrelu(acc[mt][nt][r]));
    __syncthreads();

    #pragma unroll
    for (int nt = 0; nt < 4; ++nt) {
        const float bv = b2[wave * 64 + nt * 16 + col];
        acc[0][nt] = { bv, bv, bv, bv };
        acc[1][nt] = { bv, bv, bv, bv };
    }
    mfma_gemm(&sXn[0][0], XPN, WN2s + (size_t)(wave * 4) * 8 * 512, 8, lane, acc);
    #pragma unroll
    for (int mt = 0; mt < 2; ++mt)
        #pragma unroll
        for (int nt = 0; nt < 4; ++nt)
            #pragma unroll
            for (int r = 0; r < 4; ++r) {
                const int g = r0 + mt * 16 + quad * 4 + r;
                const int n = wave * 64 + nt * 16 + col;
                out[(size_t)g * HD + n] =
                    0.5f * acc[mt][nt][r] + 0.5f * hfeat[(size_t)g * HD + n];
            }
}

// ---------------------------------------------------------------------------
// Projection MFMA: X comes from the pre-converted bf16 blob (uint4 staging).
__global__ __launch_bounds__(256, 4) void proj_mfma(
    const __hip_bfloat16* __restrict__ Xb, const __hip_bfloat16* __restrict__ Ws,
    __hip_bfloat16* __restrict__ out, int applyLrelu)
{
    __shared__ unsigned short sXp[32][XPP];
    const int tid  = threadIdx.x;
    const int lane = tid & 63;
    const int wave = tid >> 6;
    const int col  = lane & 15;
    const int quad = lane >> 4;
    const int r0   = blockIdx.x * 32;

    for (int i = tid; i < 32 * 32; i += 256) {
        const int row = i >> 5, c = i & 31;
        *reinterpret_cast<uint4*>(&sXp[row][c * 8]) =
            *reinterpret_cast<const uint4*>(&Xb[(size_t)(r0 + row) * HD + c * 8]);
    }
    __syncthreads();

    f32x4 acc[2][4];
    #pragma unroll
    for (int nt = 0; nt < 4; ++nt) {
        acc[0][nt] = { 0.f, 0.f, 0.f, 0.f };
        acc[1][nt] = { 0.f, 0.f, 0.f, 0.f };
    }
    mfma_gemm(&sXp[0][0], XPP, Ws + (size_t)(wave * 4) * 8 * 512, 8, lane, acc);
    #pragma unroll
    for (int mt = 0; mt < 2; ++mt)
        #pragma unroll
        for (int nt = 0; nt < 4; ++nt)
            #pragma unroll
            for (int r = 0; r < 4; ++r) {
                float v = acc[mt][nt][r];
                if (applyLrelu) v = lrelu(v);
                out[(size_t)(r0 + mt * 16 + quad * 4 + r) * HD +
                    wave * 64 + nt * 16 + col] = __float2bfloat16(v);
            }
}

// ---------------------------------------------------------------------------
// Attention helpers.
__device__ __forceinline__ void load_mask(
    const float* __restrict__ maskG, int transposed, int R0, int j0,
    int wave, int quad, int col, float mv[2][4])
{
    if (!transposed) {
        #pragma unroll
        for (int t = 0; t < 2; ++t)
            #pragma unroll
            for (int r = 0; r < 4; ++r)
                mv[t][r] = maskG[(size_t)(R0 + wave * 16 + quad * 4 + r) * N_REC
                                 + j0 + col + 16 * t];
    } else {
        #pragma unroll
        for (int t = 0; t < 2; ++t)
            #pragma unroll
            for (int r = 0; r < 4; ++r)
                mv[t][r] = maskG[(size_t)(j0 + col + 16 * t) * N_REC
                                 + R0 + wave * 16 + quad * 4 + r];
    }
}

// One 32-key tile with defer-max online softmax (THR=8); l kept as per-lane
// partials (reduced once at kernel end).
__device__ __forceinline__ void attn_tile(
    const unsigned short* sK, const unsigned short* sV,
    unsigned short (*sPw)[40], const bf16x8 qf[8], const float mv[2][4],
    int lane, int col, int quad, f32x4 o[16], float m[4], float l[4])
{
    // ---- S = Q K^T ----
    f32x4 sacc[2];
    sacc[0][0]=0.f; sacc[0][1]=0.f; sacc[0][2]=0.f; sacc[0][3]=0.f;
    sacc[1][0]=0.f; sacc[1][1]=0.f; sacc[1][2]=0.f; sacc[1][3]=0.f;
    #pragma unroll
    for (int t = 0; t < 2; ++t) {
        #pragma unroll
        for (int s = 0; s < 8; ++s) {
            bf16x8 kf = *reinterpret_cast<const bf16x8*>(
                &sK[(t * 8 + s) * 512 + lane * 8]);
            sacc[t] = __builtin_amdgcn_mfma_f32_16x16x32_bf16(qf[s], kf, sacc[t], 0, 0, 0);
        }
    }

    // ---- masked scores ----
    float a[2][4];
    #pragma unroll
    for (int t = 0; t < 2; ++t)
        #pragma unroll
        for (int r = 0; r < 4; ++r)
            a[t][r] = mv[t][r] * sacc[t][r] - 1000.f * (1.f - mv[t][r]);

    // ---- defer-max: rescale only when local max grows past m+8 ----
    float lm[4];
    #pragma unroll
    for (int r = 0; r < 4; ++r) lm[r] = fmaxf(a[0][r], a[1][r]);
    float w = lm[0] - m[0];
    #pragma unroll
    for (int r = 1; r < 4; ++r) w = fmaxf(w, lm[r] - m[r]);
    if (!__all(w <= 8.f)) {
        #pragma unroll
        for (int r = 0; r < 4; ++r) {
            float mx = lm[r];
            #pragma unroll
            for (int off = 1; off < 16; off <<= 1)
                mx = fmaxf(mx, __shfl_xor(mx, off));
            const float mn = fmaxf(m[r], mx);
            const float c  = __expf(m[r] - mn);
            m[r] = mn;
            l[r] *= c;
            #pragma unroll
            for (int dt = 0; dt < 16; ++dt) o[dt][r] *= c;
        }
    }

    // ---- P = exp(a - m), per-lane l partials ----
    #pragma unroll
    for (int r = 0; r < 4; ++r) {
        const float p0 = __expf(a[0][r] - m[r]);
        const float p1 = __expf(a[1][r] - m[r]);
        sPw[quad * 4 + r][col]      = f2bu(p0);
        sPw[quad * 4 + r][col + 16] = f2bu(p1);
        l[r] += p0 + p1;
    }

    // ---- O += P V ----
    bf16x8 pf = *reinterpret_cast<const bf16x8*>(&sPw[col][quad * 8]);
    #pragma unroll
    for (int dt = 0; dt < 16; ++dt) {
        bf16x8 vf = *reinterpret_cast<const bf16x8*>(&sV[dt * 512 + lane * 8]);
        o[dt] = __builtin_amdgcn_mfma_f32_16x16x32_bf16(pf, vf, o[dt], 0, 0, 0);
    }
}

// ---------------------------------------------------------------------------
// MFMA flash attention partial. 128 q-rows/block (8 waves x 16), 32-key
// tiles. K/V double-buffered in LDS via global_load_lds; masks prefetched
// one tile ahead into alternating reg sets. (r14 structure, proven.)
__global__ __launch_bounds__(512) void attn_mfma(
    const __hip_bfloat16* __restrict__ Qb, const __hip_bfloat16* __restrict__ Kz,
    const __hip_bfloat16* __restrict__ Vz, const float* __restrict__ maskG,
    float* __restrict__ PO, float* __restrict__ PM, float* __restrict__ PL,
    int M, int chunkKeys, int transposed)
{
    __shared__ unsigned short sKb[2][8192];   // 2 x 16 KB
    __shared__ unsigned short sVb[2][8192];   // 2 x 16 KB
    __shared__ unsigned short sP[8][16][40];  // 10 KB

    const int tid  = threadIdx.x;
    const int lane = tid & 63;
    const int wave = tid >> 6;
    const int col  = lane & 15;
    const int quad = lane >> 4;
    const int R0   = blockIdx.x * 128;
    const int split = blockIdx.y;
    const int jbase = split * chunkKeys;

    bf16x8 qf[8];
    {
        const __hip_bfloat16* qp =
            Qb + (size_t)(R0 + wave * 16 + col) * HD + quad * 8;
        #pragma unroll
        for (int s = 0; s < 8; ++s)
            qf[s] = *reinterpret_cast<const bf16x8*>(qp + 32 * s);
    }

    f32x4 o[16];
    #pragma unroll
    for (int dt = 0; dt < 16; ++dt) { o[dt][0]=0.f; o[dt][1]=0.f; o[dt][2]=0.f; o[dt][3]=0.f; }
    float m[4], l[4];
    #pragma unroll
    for (int r = 0; r < 4; ++r) { m[r] = -INFINITY; l[r] = 0.f; }

    float mvA[2][4], mvB[2][4];

    // ---- prologue: tile 0 -> buf0 + mvA ----
    stage_tile(Kz + (size_t)jbase * 256, &sKb[0][0], wave, lane);
    stage_tile(Vz + (size_t)jbase * 256, &sVb[0][0], wave, lane);
    load_mask(maskG, transposed, R0, jbase, wave, quad, col, mvA);

    for (int jt = 0; jt < chunkKeys; jt += 64) {
        // ===== phase A: compute tile jt (buf0, mvA); stage jt+32 =====
        asm volatile("s_waitcnt vmcnt(0)" ::: "memory");
        __builtin_amdgcn_s_barrier();
        __builtin_amdgcn_sched_barrier(0);
        stage_tile(Kz + (size_t)(jbase + jt + 32) * 256, &sKb[1][0], wave, lane);
        stage_tile(Vz + (size_t)(jbase + jt + 32) * 256, &sVb[1][0], wave, lane);
        load_mask(maskG, transposed, R0, jbase + jt + 32, wave, quad, col, mvB);
        __builtin_amdgcn_sched_barrier(0);
        attn_tile(&sKb[0][0], &sVb[0][0], sP[wave], qf, mvA,
                  lane, col, quad, o, m, l);

        // ===== phase B: compute tile jt+32 (buf1, mvB); stage jt+64 =====
        asm volatile("s_waitcnt vmcnt(0)" ::: "memory");
        __builtin_amdgcn_s_barrier();
        __builtin_amdgcn_sched_barrier(0);
        if (jt + 64 < chunkKeys) {
            stage_tile(Kz + (size_t)(jbase + jt + 64) * 256, &sKb[0][0], wave, lane);
            stage_tile(Vz + (size_t)(jbase + jt + 64) * 256, &sVb[0][0], wave, lane);
            load_mask(maskG, transposed, R0, jbase + jt + 64, wave, quad, col, mvA);
        }
        __builtin_amdgcn_sched_barrier(0);
        attn_tile(&sKb[1][0], &sVb[1][0], sP[wave], qf, mvB,
                  lane, col, quad, o, m, l);
    }

    // ---- final l reduction (per-lane partials -> 16-lane row sums) ----
    #pragma unroll
    for (int r = 0; r < 4; ++r) {
        #pragma unroll
        for (int off = 1; off < 16; off <<= 1)
            l[r] += __shfl_xor(l[r], off);
    }

    #pragma unroll
    for (int dt = 0; dt < 16; ++dt)
        #pragma unroll
        for (int r = 0; r < 4; ++r) {
            const int row = R0 + wave * 16 + quad * 4 + r;
            PO[((size_t)split * M + row) * HD + dt * 16 + col] = o[dt][r];
        }
    if (col == 0) {
        #pragma unroll
        for (int r = 0; r < 4; ++r) {
            const int row = R0 + wave * 16 + quad * 4 + r;
            PM[(size_t)split * M + row] = m[r];
            PL[(size_t)split * M + row] = l[r];
        }
    }
}

// ---------------------------------------------------------------------------
__global__ void attn_combine(
    const float* __restrict__ PO, const float* __restrict__ PM,
    const float* __restrict__ PL, __hip_bfloat16* __restrict__ Out,
    int M, int nchunks)
{
    const int idx = blockIdx.x * 256 + threadIdx.x;
    const int row = idx >> 8;
    float mmax = -INFINITY;
    for (int c = 0; c < nchunks; ++c) mmax = fmaxf(mmax, PM[(size_t)c * M + row]);
    float denom = 0.f, acc = 0.f;
    for (int c = 0; c < nchunks; ++c) {
        const float w = __expf(PM[(size_t)c * M + row] - mmax);
        denom += PL[(size_t)c * M + row] * w;
        acc   += PO[(size_t)c * M * HD + idx] * w;
    }
    Out[idx] = __float2bfloat16(acc / denom);
}

// ---------------------------------------------------------------------------
__global__ void coords_fin(
    const float* __restrict__ coords, const float* __restrict__ origc,
    const float* __restrict__ xsum, const float* __restrict__ cnt,
    float* __restrict__ out, int n)
{
    const int i = blockIdx.x * 256 + threadIdx.x;
    if (i >= n * 3) return;
    const int node = i / 3;
    const float inv = 1.f / fmaxf(cnt[node], 1.f);
    out[i] = 0.25f * origc[i] + 0.75f * coords[i] + xsum[i] * inv;
}

// ---------------------------------------------------------------------------
extern "C" void kernel_launch(void* const* d_in, const int* in_sizes, int n_in,
                              void* d_out, int out_size, void* d_ws, size_t ws_size,
                              hipStream_t stream)
{
    const float* coords_lig = (const float*)d_in[0];
    const float* h_lig      = (const float*)d_in[1];
    const float* orig_lig   = (const float*)d_in[2];
    const float* origc_lig  = (const float*)d_in[3];
    const float* coords_rec = (const float*)d_in[4];
    const float* h_rec      = (const float*)d_in[5];
    const float* orig_rec   = (const float*)d_in[6];
    const float* origc_rec  = (const float*)d_in[7];
    const float* mask       = (const float*)d_in[8];
    const float* lig_ef     = (const float*)d_in[9];
    const float* rec_ef     = (const float*)d_in[10];
    const int* lig_src = (const int*)d_in[11];
    const int* lig_dst = (const int*)d_in[12];
    const int* rec_src = (const int*)d_in[13];
    const int* rec_dst = (const int*)d_in[14];
    const float* le_w1 = (const float*)d_in[15];
    const float* le_b1 = (const float*)d_in[16];
    const float* le_w2 = (const float*)d_in[17];
    const float* le_b2 = (const float*)d_in[18];
    const float* re_w1 = (const float*)d_in[19];
    const float* re_b1 = (const float*)d_in[20];
    const float* re_w2 = (const float*)d_in[21];
    const float* re_b2 = (const float*)d_in[22];
    const float* aql_w = (const float*)d_in[23];
    const float* akl_w = (const float*)d_in[24];
    const float* avl_w = (const float*)d_in[25];
    const float* aqr_w = (const float*)d_in[26];
    const float* akr_w = (const float*)d_in[27];
    const float* avr_w = (const float*)d_in[28];
    const float* nl_w1 = (const float*)d_in[29];
    const float* nl_b1 = (const float*)d_in[30];
    const float* nl_w2 = (const float*)d_in[31];
    const float* nl_b2 = (const float*)d_in[32];
    const float* nr_w1 = (const float*)d_in[33];
    const float* nr_b1 = (const float*)d_in[34];
    const float* nr_w2 = (const float*)d_in[35];
    const float* nr_b2 = (const float*)d_in[36];
    const float* cl_w1 = (const float*)d_in[37];
    const float* cl_b1 = (const float*)d_in[38];
    const float* cl_w2 = (const float*)d_in[39];
    const float* cl_b2 = (const float*)d_in[40];
    const float* cr_w1 = (const float*)d_in[41];
    const float* cr_b1 = (const float*)d_in[42];
    const float* cr_w2 = (const float*)d_in[43];
    const float* cr_b2 = (const float*)d_in[44];

    float* out = (float*)d_out;
    float* wsf = (float*)d_ws;

    // ---- fp32 accumulator + CSR zone ----
    const size_t AGGRL = 0;
    const size_t AGGRR = AGGRL + (size_t)N_LIG * HD;
    const size_t CNTL  = AGGRR + (size_t)N_REC * HD;
    const size_t CNTR  = CNTL + N_LIG;
    const size_t XSUML = CNTR + N_REC;
    const size_t XSUMR = XSUML + (size_t)N_LIG * 3;
    const size_t HISTL = XSUMR + (size_t)N_REC * 3;
    const size_t CURL  = HISTL + N_LIG;
    const size_t HISTR = CURL + N_LIG;
    const size_t CURR  = HISTR + N_REC;
    const size_t ZEND  = CURR + N_REC;          // zeroed through here
    const size_t ELISTL = ZEND;                 // not zeroed
    const size_t ELISTR = ELISTL + E_LIG_N;
    const size_t FEND   = ELISTR + E_REC_N;

    // ---- bf16 zone ----
    __hip_bfloat16* wsb = (__hip_bfloat16*)(wsf + FEND);
    const size_t QL  = 0;
    const size_t KL  = QL + (size_t)N_LIG * HD;
    const size_t VL  = KL + (size_t)N_LIG * HD;
    const size_t QR  = VL + (size_t)N_LIG * HD;
    const size_t KR  = QR + (size_t)N_REC * HD;
    const size_t VR  = KR + (size_t)N_REC * HD;
    const size_t CRL = VR + (size_t)N_REC * HD;
    const size_t CRR = CRL + (size_t)N_LIG * HD;
    const size_t KZL = CRR + (size_t)N_REC * HD;          // K swizzled lig
    const size_t VZL = KZL + (size_t)N_LIG * HD;          // V swizzled lig
    const size_t KZR = VZL + (size_t)N_LIG * HD;          // K swizzled rec
    const size_t VZR = KZR + (size_t)N_REC * HD;          // V swizzled rec
    const size_t EW1SZ = (size_t)16 * 17 * 512;
    const size_t KW256 = (size_t)16 * 8 * 512;
    const size_t NW1SZ = (size_t)16 * 18 * 512;
    const size_t SW_EL1 = VZR + (size_t)N_REC * HD;
    const size_t SW_EL2 = SW_EL1 + EW1SZ;
    const size_t SW_EC1 = SW_EL2 + KW256;
    const size_t SW_NL1 = SW_EC1 + KW256;
    const size_t SW_NL2 = SW_NL1 + NW1SZ;
    const size_t SW_ER1 = SW_NL2 + KW256;
    const size_t SW_ER2 = SW_ER1 + EW1SZ;
    const size_t SW_EC1R = SW_ER2 + KW256;
    const size_t SW_NR1 = SW_EC1R + KW256;
    const size_t SW_NR2 = SW_NR1 + NW1SZ;
    const size_t SW_PQL = SW_NR2 + KW256;
    const size_t SW_PKL = SW_PQL + KW256;
    const size_t SW_PVL = SW_PKL + KW256;
    const size_t SW_PQR = SW_PVL + KW256;
    const size_t SW_PKR = SW_PQR + KW256;
    const size_t SW_PVR = SW_PKR + KW256;
    // pre-converted bf16 operand blobs
    const size_t HB_L  = SW_PVR + KW256;
    const size_t HB_R  = HB_L + (size_t)N_LIG * HD;
    const size_t EFB_L = HB_R + (size_t)N_REC * HD;
    const size_t EFB_R = EFB_L + (size_t)E_LIG_N * EFD;
    const size_t BF_END = EFB_R + (size_t)E_REC_N * EFD;

    // ---- split-K partial zone (fp32), dynamic splits ----
    float* wsp = (float*)(wsb + ((BF_END + 1) & ~(size_t)1));
    const size_t baseBytes = (size_t)((char*)wsp - (char*)d_ws);
    int SL = 16, SR = 4;
    {
        const size_t poElems16 = (size_t)16 * N_LIG * HD;
        const size_t need16 = baseBytes +
            (poElems16 + 2 * (size_t)16 * N_LIG) * sizeof(float);
        if (ws_size < need16) { SL = 8; SR = 2; }
    }
    const size_t PO_ = 0;
    const size_t PM_ = PO_ + (size_t)SL * N_LIG * HD;
    const size_t PL_ = PM_ + (size_t)SL * N_LIG;

    const size_t O_XL = 0;
    const size_t O_HL = O_XL + (size_t)N_LIG * 3;
    const size_t O_XR = O_HL + (size_t)N_LIG * HD;
    const size_t O_HR = O_XR + (size_t)N_REC * 3;

    // 1) zero atomic accumulators + CSR hist/cursors
    zero_kernel<<<((int)ZEND + 255) / 256, 256, 0, stream>>>(wsf, (int)ZEND);

    // 1a) fp32 -> bf16 operand blobs (h and edge features)
    f2b_kernel<<<(N_LIG * HD / 8 + 255) / 256, 256, 0, stream>>>(
        h_lig, wsb + HB_L, N_LIG * HD / 8);
    f2b_kernel<<<(N_REC * HD / 8 + 255) / 256, 256, 0, stream>>>(
        h_rec, wsb + HB_R, N_REC * HD / 8);
    f2b_kernel<<<(E_LIG_N * EFD / 8 + 255) / 256, 256, 0, stream>>>(
        lig_ef, wsb + EFB_L, E_LIG_N * EFD / 8);
    f2b_kernel<<<(E_REC_N * EFD / 8 + 255) / 256, 256, 0, stream>>>(
        rec_ef, wsb + EFB_R, E_REC_N * EFD / 8);

    // 1b) CSR build: dst-sorted edge permutations (also produces fp32 counts)
    hist_kernel<<<E_LIG_N / 256, 256, 0, stream>>>(lig_dst, (int*)(wsf + HISTL), E_LIG_N);
    hist_kernel<<<E_REC_N / 256, 256, 0, stream>>>(rec_dst, (int*)(wsf + HISTR), E_REC_N);
    scan_kernel<<<1, 256, 0, stream>>>((int*)(wsf + HISTL), (int*)(wsf + CURL),
                                       wsf + CNTL, N_LIG);
    scan_kernel<<<1, 256, 0, stream>>>((int*)(wsf + HISTR), (int*)(wsf + CURR),
                                       wsf + CNTR, N_REC);
    scatter_kernel<<<E_LIG_N / 256, 256, 0, stream>>>(
        lig_dst, (int*)(wsf + CURL), (int*)(wsf + ELISTL), E_LIG_N);
    scatter_kernel<<<E_REC_N / 256, 256, 0, stream>>>(
        rec_dst, (int*)(wsf + CURR), (int*)(wsf + ELISTR), E_REC_N);

    // 2) weight swizzles
    wt_swz<<<16 * 17, 256, 0, stream>>>(le_w1, wsb + SW_EL1, EIN, 17);
    wt_swz<<<16 * 8,  256, 0, stream>>>(le_w2, wsb + SW_EL2, 256, 8);
    wt_swz<<<16 * 8,  256, 0, stream>>>(cl_w1, wsb + SW_EC1, 256, 8);
    wt_swz<<<16 * 18, 256, 0, stream>>>(nl_w1, wsb + SW_NL1, 576, 18);
    wt_swz<<<16 * 8,  256, 0, stream>>>(nl_w2, wsb + SW_NL2, 256, 8);
    wt_swz<<<16 * 17, 256, 0, stream>>>(re_w1, wsb + SW_ER1, EIN, 17);
    wt_swz<<<16 * 8,  256, 0, stream>>>(re_w2, wsb + SW_ER2, 256, 8);
    wt_swz<<<16 * 8,  256, 0, stream>>>(cr_w1, wsb + SW_EC1R, 256, 8);
    wt_swz<<<16 * 18, 256, 0, stream>>>(nr_w1, wsb + SW_NR1, 576, 18);
    wt_swz<<<16 * 8,  256, 0, stream>>>(nr_w2, wsb + SW_NR2, 256, 8);
    wt_swz<<<16 * 8,  256, 0, stream>>>(aql_w, wsb + SW_PQL, 256, 8);
    wt_swz<<<16 * 8,  256, 0, stream>>>(akl_w, wsb + SW_PKL, 256, 8);
    wt_swz<<<16 * 8,  256, 0, stream>>>(avl_w, wsb + SW_PVL, 256, 8);
    wt_swz<<<16 * 8,  256, 0, stream>>>(aqr_w, wsb + SW_PQR, 256, 8);
    wt_swz<<<16 * 8,  256, 0, stream>>>(akr_w, wsb + SW_PKR, 256, 8);
    wt_swz<<<16 * 8,  256, 0, stream>>>(avr_w, wsb + SW_PVR, 256, 8);

    // 3) edge MFMA kernels (dst-sorted order, segmented atomics, bf16 blobs)
    edge_mfma<<<E_LIG_N / 32, 256, 0, stream>>>(
        coords_lig, wsb + HB_L, wsb + EFB_L, lig_src, lig_dst,
        (const int*)(wsf + ELISTL),
        wsb + SW_EL1, le_b1, wsb + SW_EL2, le_b2, wsb + SW_EC1, cl_b1, cl_w2, cl_b2,
        wsf + AGGRL, wsf + XSUML);
    edge_mfma<<<E_REC_N / 32, 256, 0, stream>>>(
        coords_rec, wsb + HB_R, wsb + EFB_R, rec_src, rec_dst,
        (const int*)(wsf + ELISTR),
        wsb + SW_ER1, re_b1, wsb + SW_ER2, re_b2, wsb + SW_EC1R, cr_b1, cr_w2, cr_b2,
        wsf + AGGRR, wsf + XSUMR);

    // 4) projections -> bf16 (MFMA), then K/V fragment swizzles
    proj_mfma<<<N_LIG / 32, 256, 0, stream>>>(wsb + HB_L, wsb + SW_PQL, wsb + QL, 1);
    proj_mfma<<<N_LIG / 32, 256, 0, stream>>>(wsb + HB_L, wsb + SW_PKL, wsb + KL, 1);
    proj_mfma<<<N_LIG / 32, 256, 0, stream>>>(wsb + HB_L, wsb + SW_PVL, wsb + VL, 0);
    proj_mfma<<<N_REC / 32, 256, 0, stream>>>(wsb + HB_R, wsb + SW_PQR, wsb + QR, 1);
    proj_mfma<<<N_REC / 32, 256, 0, stream>>>(wsb + HB_R, wsb + SW_PKR, wsb + KR, 1);
    proj_mfma<<<N_REC / 32, 256, 0, stream>>>(wsb + HB_R, wsb + SW_PVR, wsb + VR, 0);
    kswz_kernel<<<N_LIG / 8, 256, 0, stream>>>(wsb + KL, wsb + KZL);
    kswz_kernel<<<N_REC / 8, 256, 0, stream>>>(wsb + KR, wsb + KZR);
    vswz_kernel<<<N_LIG / 32, 256, 0, stream>>>(wsb + VL, wsb + VZL);
    vswz_kernel<<<N_REC / 32, 256, 0, stream>>>(wsb + VR, wsb + VZR);

    // 5) MFMA flash attention, split-K + combine
    {
        dim3 gl(N_LIG / 128, SL);
        attn_mfma<<<gl, 512, 0, stream>>>(wsb + QL, wsb + KZR, wsb + VZR, mask,
                                          wsp + PO_, wsp + PM_, wsp + PL_,
                                          N_LIG, N_REC / SL, 0);
        attn_combine<<<N_LIG, 256, 0, stream>>>(
            wsp + PO_, wsp + PM_, wsp + PL_, wsb + CRL, N_LIG, SL);

        dim3 gr(N_REC / 128, SR);
        attn_mfma<<<gr, 512, 0, stream>>>(wsb + QR, wsb + KZL, wsb + VZL, mask,
                                          wsp + PO_, wsp + PM_, wsp + PL_,
                                          N_REC, N_LIG / SR, 1);
        attn_combine<<<N_REC, 256, 0, stream>>>(
            wsp + PO_, wsp + PM_, wsp + PL_, wsb + CRR, N_REC, SR);
    }

    // 6) coordinate outputs
    coords_fin<<<(N_LIG * 3 + 255) / 256, 256, 0, stream>>>(
        coords_lig, origc_lig, wsf + XSUML, wsf + CNTL, out + O_XL, N_LIG);
    coords_fin<<<(N_REC * 3 + 255) / 256, 256, 0, stream>>>(
        coords_rec, origc_rec, wsf + XSUMR, wsf + CNTR, out + O_XR, N_REC);

    // 7) node MFMA kernels
    node_mfma<<<N_LIG / 32, 256, 0, stream>>>(
        wsf + AGGRL, wsf + CNTL, wsb + CRL, orig_lig, h_lig,
        wsb + SW_NL1, nl_b1, wsb + SW_NL2, nl_b2, out + O_HL);
    node_mfma<<<N_REC / 32, 256, 0, stream>>>(
        wsf + AGGRR, wsf + CNTR, wsb + CRR, orig_rec, h_rec,
        wsb + SW_NR1, nr_b1, wsb + SW_NR2, nr_b2, out + O_HR);

    (void)in_sizes; (void)n_in; (void)out_size;
}